// Round 12
// baseline (222.425 us; speedup 1.0000x reference)
//
#include <hip/hip_runtime.h>
#include <cstdint>
#include <cstddef>

// Problem constants (fixed by setup_inputs)
constexpr int R_ = 2048;   // reg_len
constexpr int B_ = 2;      // batch
constexpr int S_ = 128;    // sum_len
constexpr int E_ = 512;    // embed dim
constexpr int H_ = 8;      // heads
constexpr int D_ = 64;     // head dim
constexpr int N_ = R_ * B_;            // 4096 token rows
constexpr float SCALE_ = 0.125f;       // D^-0.5
constexpr float LOG2E_ = 1.44269504088896340736f;
constexpr float SLOG2E_ = SCALE_ * LOG2E_;   // folded into Q scales (exp2 domain)

typedef short bf8_t __attribute__((ext_vector_type(8)));   // 8 bf16 in 4 VGPRs
typedef float f32x4 __attribute__((ext_vector_type(4)));
typedef float f32x16 __attribute__((ext_vector_type(16)));
typedef unsigned u32x4 __attribute__((ext_vector_type(4)));

#define MFMA16(a, b, c) __builtin_amdgcn_mfma_f32_16x16x32_bf16((a), (b), (c), 0, 0, 0)
#define MFMA32(a, b, c) __builtin_amdgcn_mfma_f32_32x32x16_bf16((a), (b), (c), 0, 0, 0)

__device__ __forceinline__ unsigned short f2bf(float f) {
  unsigned u = __builtin_bit_cast(unsigned, f);
  unsigned r = u + 0x7FFFu + ((u >> 16) & 1u);   // RNE
  return (unsigned short)(r >> 16);
}
__device__ __forceinline__ float bf2f(unsigned short h) {
  unsigned u = ((unsigned)h) << 16;
  return __builtin_bit_cast(float, u);
}
// kv-permutation (swap bits 2<->3 within each 16) for V^T storage; involution.
__device__ __forceinline__ int kvperm(int kv) {
  return (kv & ~15) | (kv & 3) | ((kv & 4) << 1) | ((kv & 8) >> 1);
}
// async global->LDS, 16B per lane (dst = wave-uniform base + lane*16)
__device__ __forceinline__ void gload16(const unsigned short* g, unsigned short* l) {
  __builtin_amdgcn_global_load_lds(
      (const __attribute__((address_space(1))) unsigned*)g,
      (__attribute__((address_space(3))) unsigned*)l, 16, 0, 0);
}

// ---------------------------------------------------------------------------
// Fused precision splits + gather (one launch)
// ---------------------------------------------------------------------------
struct WSplitJob { const float* src; unsigned short* dst; };
struct WSplit7 { WSplitJob j[7]; };

__global__ __launch_bounds__(256)
void fused_split_kernel(const float* __restrict__ reg_x, unsigned short* __restrict__ Apair,
                        WSplit7 P, const float* __restrict__ table,
                        const int* __restrict__ ids,
                        unsigned short* __restrict__ sqhi, unsigned short* __restrict__ sqlo)
{
  const int bx = blockIdx.x;
  const int tid = threadIdx.x;
  if (bx < 8192) {
    const int idx = bx * 256 + tid;                 // < 4096*512
    const int r = idx >> 9, c = idx & 511;
    const float v = reg_x[idx];
    const unsigned short hi = f2bf(v);
    unsigned short* d = Apair + ((size_t)r << 10) + c;
    d[0] = hi; d[512] = f2bf(v - bf2f(hi));
  } else if (bx < 15360) {
    const int bj = bx - 8192;
    const WSplitJob jb = P.j[bj >> 10];
    const int idx = (bj & 1023) * 256 + tid;        // < 512*512
    const int r = idx >> 9, c = idx & 511;
    const float v = jb.src[idx];
    const unsigned short hi = f2bf(v);
    const unsigned short lo = f2bf(v - bf2f(hi));
    unsigned short* d = jb.dst + (size_t)r * 1536 + c;
    d[0] = hi; d[512] = hi; d[1024] = lo;
  } else {
    const int idx = (bx - 15360) * 256 + tid;       // < B*H*S*D = 131072
    const int d = idx & 63;
    const int s = (idx >> 6) & 127;
    const int h = (idx >> 13) & 7;
    const int b = idx >> 16;
    const float v = table[(size_t)ids[b * S_ + s] * E_ + h * 64 + d] * SLOG2E_;
    const unsigned short hi = f2bf(v);
    sqhi[idx] = hi;
    sqlo[idx] = f2bf(v - bf2f(hi));
  }
}

// ---------------------------------------------------------------------------
// Split-precision MFMA GEMM (T14 reg-prefetch staging).  [R7-proven]
// Used for gate/final GEMMs (256-block grids).
// ---------------------------------------------------------------------------
struct GemmOut {
  const unsigned short* W;
  const float* bias;
  float scale;
  float* Cf;
  unsigned short* hi;
  unsigned short* lo;
  int mode;
};
struct GemmOuts4 { GemmOut o[4]; };

__global__ __launch_bounds__(256, 4)
void gemm_split_kernel(const unsigned short* __restrict__ A, GemmOuts4 P)
{
  const GemmOut g = P.o[blockIdx.z];
  __shared__ unsigned short As[128][48];
  __shared__ unsigned short Ws[64][48];

  const int tid = threadIdx.x;
  const int w = tid >> 6;          // wave 0..3
  const int l = tid & 63;
  const int lr = l & 15;
  const int lg = l >> 4;
  const int n0 = blockIdx.x * 128;
  const int o0 = blockIdx.y * 64;

  f32x4 acc[2][4];
#pragma unroll
  for (int m = 0; m < 2; ++m)
#pragma unroll
    for (int n = 0; n < 4; ++n) acc[m][n] = (f32x4){0.f, 0.f, 0.f, 0.f};

  const int ar = tid >> 1;          // 0..127
  const int ac = (tid & 1) * 16;
  const int wr = tid >> 2;          // 0..63
  const int wc = (tid & 3) * 8;

  bf8_t ra0 = *(const bf8_t*)(A + (size_t)(n0 + ar) * 1024 + ac);
  bf8_t ra1 = *(const bf8_t*)(A + (size_t)(n0 + ar) * 1024 + ac + 8);
  bf8_t rw0 = *(const bf8_t*)(g.W + (size_t)(o0 + wr) * 1536 + wc);

  for (int k0 = 0; k0 < 1536; k0 += 32) {
    __syncthreads();
    *(bf8_t*)&As[ar][ac] = ra0;
    *(bf8_t*)&As[ar][ac + 8] = ra1;
    *(bf8_t*)&Ws[wr][wc] = rw0;
    __syncthreads();
    if (k0 + 32 < 1536) {
      const int ak = (k0 + 32) & 1023;
      ra0 = *(const bf8_t*)(A + (size_t)(n0 + ar) * 1024 + ak + ac);
      ra1 = *(const bf8_t*)(A + (size_t)(n0 + ar) * 1024 + ak + ac + 8);
      rw0 = *(const bf8_t*)(g.W + (size_t)(o0 + wr) * 1536 + k0 + 32 + wc);
    }

    bf8_t bvs[4];
#pragma unroll
    for (int n = 0; n < 4; ++n)
      bvs[n] = *(const bf8_t*)&Ws[n * 16 + lr][lg * 8];
#pragma unroll
    for (int m = 0; m < 2; ++m) {
      bf8_t av = *(const bf8_t*)&As[w * 32 + m * 16 + lr][lg * 8];
#pragma unroll
      for (int n = 0; n < 4; ++n)
        acc[m][n] = MFMA16(av, bvs[n], acc[m][n]);
    }
  }

#pragma unroll
  for (int m = 0; m < 2; ++m)
#pragma unroll
    for (int n = 0; n < 4; ++n)
#pragma unroll
      for (int r = 0; r < 4; ++r) {
        const int row = n0 + w * 32 + m * 16 + lg * 4 + r;
        const int col = o0 + n * 16 + lr;
        float v = acc[m][n][r];
        if (g.bias) v += g.bias[col];
        v *= g.scale;
        if (g.mode == 0) {
          g.Cf[((size_t)row << 9) + col] = v;
        } else {
          const int bb = row & 1, rr = row >> 1;
          const int hh = col >> 6, dd = col & 63;
          size_t id;
          if (g.mode == 1) id = (((size_t)(bb * H_ + hh) * R_) + rr) * 64 + dd;
          else             id = (((size_t)(bb * H_ + hh) * 64) + dd) * R_ + kvperm(rr);
          const unsigned short hv = f2bf(v);
          g.hi[id] = hv;
          g.lo[id] = f2bf(v - bf2f(hv));
        }
      }
}

// ---------------------------------------------------------------------------
// m97-structure GEMM for the 4 projections: 128x128 tile, 64x64 per wave,
// double-buffered LDS fed by global_load_lds (width 16).  512-block grid.
// A: bf16 [M][1024] (hi|lo), logical K=1536 with A col wrap mod 1024.
// W: bf16 [512][1536] (hi|hi|lo).
// mode 1: hi/lo pair -> [bh][row>>1][col&63]
// mode 2: hi/lo pair -> [bh][col&63][kvperm(row>>1)]  (transposed V layout)
// ---------------------------------------------------------------------------
struct GOut {
  const unsigned short* W;
  const float* bias;
  float scale;
  unsigned short* hi;
  unsigned short* lo;
  int mode;
};
struct GOuts4 { GOut o[4]; };

__global__ __launch_bounds__(256, 3)
void gemm128_kernel(const unsigned short* __restrict__ A, GOuts4 P)
{
  const GOut g = P.o[blockIdx.z];
  __shared__ unsigned short As[2][4096];   // 128 rows x 32 k, linear
  __shared__ unsigned short Ws[2][4096];

  const int tid = threadIdx.x;
  const int w = tid >> 6;
  const int l = tid & 63;
  const int lr = l & 15;
  const int lg = l >> 4;
  const int wr = (w >> 1) * 64;    // wave row base in tile
  const int wc = (w & 1) * 64;     // wave col base in tile
  const int n0 = blockIdx.x * 128;
  const int o0 = blockIdx.y * 128;

  // per-lane staging source bases (two 16-row groups each for A and W)
  const int srow = w * 32 + (l >> 2);
  const int scol = (l & 3) * 8;
  const unsigned short* A0 = A + (size_t)(n0 + srow) * 1024 + scol;
  const unsigned short* A1 = A0 + (size_t)16 * 1024;
  const unsigned short* W0 = g.W + (size_t)(o0 + srow) * 1536 + scol;
  const unsigned short* W1 = W0 + (size_t)16 * 1536;

  f32x4 acc[4][4];
#pragma unroll
  for (int m = 0; m < 4; ++m)
#pragma unroll
    for (int n = 0; n < 4; ++n) acc[m][n] = (f32x4){0.f, 0.f, 0.f, 0.f};

  // prologue: stage t=0 into buf 0
  gload16(A0, &As[0][w * 1024]);
  gload16(A1, &As[0][w * 1024 + 512]);
  gload16(W0, &Ws[0][w * 1024]);
  gload16(W1, &Ws[0][w * 1024 + 512]);
  __syncthreads();

  int buf = 0;
  for (int t = 0; t < 48; ++t) {
    if (t + 1 < 48) {   // prefetch next K-step into the other buffer
      const int ak = ((t + 1) * 32) & 1023;
      const int wk = (t + 1) * 32;
      gload16(A0 + ak, &As[buf ^ 1][w * 1024]);
      gload16(A1 + ak, &As[buf ^ 1][w * 1024 + 512]);
      gload16(W0 + wk, &Ws[buf ^ 1][w * 1024]);
      gload16(W1 + wk, &Ws[buf ^ 1][w * 1024 + 512]);
    }
    bf8_t av[4], bv[4];
#pragma unroll
    for (int m = 0; m < 4; ++m)
      av[m] = *(const bf8_t*)&As[buf][(wr + m * 16 + lr) * 32 + lg * 8];
#pragma unroll
    for (int n = 0; n < 4; ++n)
      bv[n] = *(const bf8_t*)&Ws[buf][(wc + n * 16 + lr) * 32 + lg * 8];
    __builtin_amdgcn_s_setprio(1);
#pragma unroll
    for (int m = 0; m < 4; ++m)
#pragma unroll
      for (int n = 0; n < 4; ++n)
        acc[m][n] = MFMA16(av[m], bv[n], acc[m][n]);
    __builtin_amdgcn_s_setprio(0);
    __syncthreads();   // drains gload queue + LDS reads
    buf ^= 1;
  }

#pragma unroll
  for (int m = 0; m < 4; ++m)
#pragma unroll
    for (int n = 0; n < 4; ++n)
#pragma unroll
      for (int r = 0; r < 4; ++r) {
        const int row = n0 + wr + m * 16 + lg * 4 + r;
        const int col = o0 + wc + n * 16 + lr;
        float v = acc[m][n][r];
        if (g.bias) v += g.bias[col];
        v *= g.scale;
        const int bb = row & 1, rr = row >> 1;
        const int hh = col >> 6, dd = col & 63;
        size_t id;
        if (g.mode == 1) id = (((size_t)(bb * H_ + hh) * R_) + rr) * 64 + dd;
        else             id = (((size_t)(bb * H_ + hh) * 64) + dd) * R_ + kvperm(rr);
        const unsigned short hv = f2bf(v);
        g.hi[id] = hv;
        g.lo[id] = f2bf(v - bf2f(hv));
      }
}

// ---------------------------------------------------------------------------
// Fused gate GEMMs + sigmoid + blend.  [R7-proven]
// ---------------------------------------------------------------------------
__global__ __launch_bounds__(256, 4)
void gate_blend_gemm_kernel(const unsigned short* __restrict__ A1,
                            const unsigned short* __restrict__ A2,
                            const unsigned short* __restrict__ W1,
                            const unsigned short* __restrict__ W2,
                            const float* __restrict__ gb,
                            unsigned short* __restrict__ attnP)
{
  __shared__ unsigned short As[128][48];
  __shared__ unsigned short Ws[64][48];

  const int tid = threadIdx.x;
  const int w = tid >> 6;
  const int l = tid & 63;
  const int lr = l & 15;
  const int lg = l >> 4;
  const int n0 = blockIdx.x * 128;
  const int o0 = blockIdx.y * 64;

  f32x4 acc[2][4];
#pragma unroll
  for (int m = 0; m < 2; ++m)
#pragma unroll
    for (int n = 0; n < 4; ++n) acc[m][n] = (f32x4){0.f, 0.f, 0.f, 0.f};

  const int ar = tid >> 1;
  const int ac = (tid & 1) * 16;
  const int wr = tid >> 2;
  const int wc = (tid & 3) * 8;

  auto aP = [&](int kk) {
    const unsigned short* Ax = (kk < 48) ? A1 : A2;
    const int k0 = ((kk < 48) ? kk : kk - 48) * 32;
    return Ax + (size_t)(n0 + ar) * 1024 + (k0 & 1023) + ac;
  };
  auto wP = [&](int kk) {
    const unsigned short* Wx = (kk < 48) ? W1 : W2;
    const int k0 = ((kk < 48) ? kk : kk - 48) * 32;
    return Wx + (size_t)(o0 + wr) * 1536 + k0 + wc;
  };

  bf8_t ra0 = *(const bf8_t*)aP(0);
  bf8_t ra1 = *(const bf8_t*)(aP(0) + 8);
  bf8_t rw0 = *(const bf8_t*)wP(0);

  for (int kk = 0; kk < 96; ++kk) {
    __syncthreads();
    *(bf8_t*)&As[ar][ac] = ra0;
    *(bf8_t*)&As[ar][ac + 8] = ra1;
    *(bf8_t*)&Ws[wr][wc] = rw0;
    __syncthreads();
    if (kk + 1 < 96) {
      ra0 = *(const bf8_t*)aP(kk + 1);
      ra1 = *(const bf8_t*)(aP(kk + 1) + 8);
      rw0 = *(const bf8_t*)wP(kk + 1);
    }

    bf8_t bvs[4];
#pragma unroll
    for (int n = 0; n < 4; ++n)
      bvs[n] = *(const bf8_t*)&Ws[n * 16 + lr][lg * 8];
#pragma unroll
    for (int m = 0; m < 2; ++m) {
      bf8_t av = *(const bf8_t*)&As[w * 32 + m * 16 + lr][lg * 8];
#pragma unroll
      for (int n = 0; n < 4; ++n)
        acc[m][n] = MFMA16(av, bvs[n], acc[m][n]);
    }
  }

#pragma unroll
  for (int m = 0; m < 2; ++m)
#pragma unroll
    for (int n = 0; n < 4; ++n)
#pragma unroll
      for (int r = 0; r < 4; ++r) {
        const int row = n0 + w * 32 + m * 16 + lg * 4 + r;
        const int col = o0 + n * 16 + lr;
        const float t = acc[m][n][r] + gb[col];
        const float gt = 1.0f / (1.0f + __expf(-t));
        const size_t base = (size_t)row << 10;
        const float so = bf2f(A1[base + col]) + bf2f(A1[base + 512 + col]);
        const float ro = bf2f(A2[base + col]) + bf2f(A2[base + 512 + col]);
        const float a = gt * so + (1.0f - gt) * ro;
        const unsigned short hv = f2bf(a);
        attnP[base + col] = hv;
        attnP[base + 512 + col] = f2bf(a - bf2f(hv));
      }
}

// ---------------------------------------------------------------------------
// Split-precision 32x32x16 flash attention body.  [R9/R11-proven]
// ---------------------------------------------------------------------------
struct FArgs {
  const unsigned short *Qhi, *Qlo, *Khi, *Klo, *VtHi, *VtLo;
  int q_len, kv_len, chunk, zsplit, out_mode;
  float *accA, *accB, *mlP;
  unsigned short* OutP;
};

__device__ __forceinline__
void flash_body(const FArgs& A, const int bh, const int q0blk, const int c)
{
  __shared__ unsigned short KsH[64][72];
  __shared__ unsigned short KsL[64][72];
  __shared__ unsigned short VsH[64][72];
  __shared__ unsigned short VsL[64][72];

  const int tid = threadIdx.x;
  const int w = tid >> 6;
  const int l = tid & 63;
  const int lq = l & 31;
  const int hi = l >> 5;
  const int q0 = q0blk * 128;
  const int kvbeg = c * A.chunk;
  const int kvend = kvbeg + A.chunk;
  const int qrow = q0 + w * 32 + lq;

  bf8_t qh[4], ql[4];
  {
    const size_t qbase = ((size_t)bh * A.q_len + qrow) * 64;
#pragma unroll
    for (int kd = 0; kd < 4; ++kd) {
      qh[kd] = *(const bf8_t*)(A.Qhi + qbase + kd * 16 + hi * 8);
      ql[kd] = *(const bf8_t*)(A.Qlo + qbase + kd * 16 + hi * 8);
    }
  }

  f32x16 acc0 = {0,0,0,0,0,0,0,0,0,0,0,0,0,0,0,0};
  f32x16 acc1 = {0,0,0,0,0,0,0,0,0,0,0,0,0,0,0,0};
  float mrow = -INFINITY;
  float lrow = 0.0f;

  const int sr = tid >> 2;            // staging row 0..63
  const int sc = (tid & 3) * 16;      // staging col

  bf8_t rkh[2], rkl[2], rvh[2], rvl[2];
  {
    const size_t kb = ((size_t)bh * A.kv_len + kvbeg + sr) * 64 + sc;
    rkh[0] = *(const bf8_t*)(A.Khi + kb);  rkh[1] = *(const bf8_t*)(A.Khi + kb + 8);
    rkl[0] = *(const bf8_t*)(A.Klo + kb);  rkl[1] = *(const bf8_t*)(A.Klo + kb + 8);
    const size_t vb = ((size_t)bh * 64 + sr) * A.kv_len + kvbeg + sc;
    rvh[0] = *(const bf8_t*)(A.VtHi + vb); rvh[1] = *(const bf8_t*)(A.VtHi + vb + 8);
    rvl[0] = *(const bf8_t*)(A.VtLo + vb); rvl[1] = *(const bf8_t*)(A.VtLo + vb + 8);
  }

  for (int kv0 = kvbeg; kv0 < kvend; kv0 += 64) {
    __syncthreads();
    *(bf8_t*)&KsH[sr][sc] = rkh[0];  *(bf8_t*)&KsH[sr][sc + 8] = rkh[1];
    *(bf8_t*)&KsL[sr][sc] = rkl[0];  *(bf8_t*)&KsL[sr][sc + 8] = rkl[1];
    *(bf8_t*)&VsH[sr][sc] = rvh[0];  *(bf8_t*)&VsH[sr][sc + 8] = rvh[1];
    *(bf8_t*)&VsL[sr][sc] = rvl[0];  *(bf8_t*)&VsL[sr][sc + 8] = rvl[1];
    __syncthreads();
    if (kv0 + 64 < kvend) {
      const size_t kb = ((size_t)bh * A.kv_len + kv0 + 64 + sr) * 64 + sc;
      rkh[0] = *(const bf8_t*)(A.Khi + kb);  rkh[1] = *(const bf8_t*)(A.Khi + kb + 8);
      rkl[0] = *(const bf8_t*)(A.Klo + kb);  rkl[1] = *(const bf8_t*)(A.Klo + kb + 8);
      const size_t vb = ((size_t)bh * 64 + sr) * A.kv_len + kv0 + 64 + sc;
      rvh[0] = *(const bf8_t*)(A.VtHi + vb); rvh[1] = *(const bf8_t*)(A.VtHi + vb + 8);
      rvl[0] = *(const bf8_t*)(A.VtLo + vb); rvl[1] = *(const bf8_t*)(A.VtLo + vb + 8);
    }

    // ---- QK^T swapped (24 MFMA32)
    f32x16 s0 = {0,0,0,0,0,0,0,0,0,0,0,0,0,0,0,0};
    f32x16 s1 = {0,0,0,0,0,0,0,0,0,0,0,0,0,0,0,0};
    __builtin_amdgcn_s_setprio(1);
#pragma unroll
    for (int kd = 0; kd < 4; ++kd) {
      const bf8_t kfh0 = *(const bf8_t*)&KsH[lq][kd * 16 + hi * 8];
      const bf8_t kfl0 = *(const bf8_t*)&KsL[lq][kd * 16 + hi * 8];
      s0 = MFMA32(kfh0, qh[kd], s0);
      s0 = MFMA32(kfh0, ql[kd], s0);
      s0 = MFMA32(kfl0, qh[kd], s0);
      const bf8_t kfh1 = *(const bf8_t*)&KsH[32 + lq][kd * 16 + hi * 8];
      const bf8_t kfl1 = *(const bf8_t*)&KsL[32 + lq][kd * 16 + hi * 8];
      s1 = MFMA32(kfh1, qh[kd], s1);
      s1 = MFMA32(kfh1, ql[kd], s1);
      s1 = MFMA32(kfl1, qh[kd], s1);
    }
    __builtin_amdgcn_s_setprio(0);

    // ---- online softmax (exp2 domain), defer-max (THR = 8)
    float mx = fmaxf(s0[0], s1[0]);
#pragma unroll
    for (int r = 1; r < 16; ++r) mx = fmaxf(mx, fmaxf(s0[r], s1[r]));
    mx = fmaxf(mx, __shfl_xor(mx, 32));
    if (mx > mrow + 8.0f) {
      const float f = exp2f(mrow - mx);
      mrow = mx;
      lrow *= f;
#pragma unroll
      for (int r = 0; r < 16; ++r) { acc0[r] *= f; acc1[r] *= f; }
    }
    float ts = 0.f;
#pragma unroll
    for (int r = 0; r < 16; ++r) { s0[r] = exp2f(s0[r] - mrow); ts += s0[r]; }
#pragma unroll
    for (int r = 0; r < 16; ++r) { s1[r] = exp2f(s1[r] - mrow); ts += s1[r]; }
    ts += __shfl_xor(ts, 32);
    lrow += ts;

    // ---- P pack: trunc hi + trunc lo via v_perm_b32 (lane-local)
    bf8_t pah[4], pal[4];
    const unsigned sel = 0x07060302u;
#pragma unroll
    for (int n = 0; n < 2; ++n)
#pragma unroll
      for (int ks = 0; ks < 2; ++ks) {
        u32x4 hp, lp;
#pragma unroll
        for (int p2 = 0; p2 < 4; ++p2) {
          const float a = n ? s1[ks * 8 + p2 * 2]     : s0[ks * 8 + p2 * 2];
          const float b = n ? s1[ks * 8 + p2 * 2 + 1] : s0[ks * 8 + p2 * 2 + 1];
          const unsigned ua = __builtin_bit_cast(unsigned, a);
          const unsigned ub = __builtin_bit_cast(unsigned, b);
          hp[p2] = __builtin_amdgcn_perm(ub, ua, sel);
          const float la = a - __builtin_bit_cast(float, ua & 0xFFFF0000u);
          const float lb = b - __builtin_bit_cast(float, ub & 0xFFFF0000u);
          lp[p2] = __builtin_amdgcn_perm(__builtin_bit_cast(unsigned, lb),
                                         __builtin_bit_cast(unsigned, la), sel);
        }
        pah[n * 2 + ks] = __builtin_bit_cast(bf8_t, hp);
        pal[n * 2 + ks] = __builtin_bit_cast(bf8_t, lp);
      }

    // ---- PV (24 MFMA32); V^T permuted-contiguous b128 reads
    __builtin_amdgcn_s_setprio(1);
#pragma unroll
    for (int n = 0; n < 2; ++n)
#pragma unroll
      for (int ks = 0; ks < 2; ++ks) {
        const int vcol = n * 32 + ks * 16 + hi * 8;
        const bf8_t ph = pah[n * 2 + ks];
        const bf8_t pl = pal[n * 2 + ks];
        {
          const bf8_t vfh = *(const bf8_t*)&VsH[lq][vcol];
          const bf8_t vfl = *(const bf8_t*)&VsL[lq][vcol];
          acc0 = MFMA32(vfh, ph, acc0);
          acc0 = MFMA32(vfh, pl, acc0);
          acc0 = MFMA32(vfl, ph, acc0);
        }
        {
          const bf8_t vfh = *(const bf8_t*)&VsH[32 + lq][vcol];
          const bf8_t vfl = *(const bf8_t*)&VsL[32 + lq][vcol];
          acc1 = MFMA32(vfh, ph, acc1);
          acc1 = MFMA32(vfh, pl, acc1);
          acc1 = MFMA32(vfl, ph, acc1);
        }
      }
    __builtin_amdgcn_s_setprio(0);
  }

  if (A.out_mode == 0) {
    const size_t cstride = (size_t)16 * A.q_len * 64;
    float* accbase = (c < A.zsplit) ? A.accA + (size_t)c * cstride
                                    : A.accB + (size_t)(c - A.zsplit) * cstride;
    float* rowp = accbase + ((size_t)bh * A.q_len + qrow) * 64;
#pragma unroll
    for (int rg = 0; rg < 4; ++rg) {
      *(float4*)(rowp + rg * 8 + hi * 4) =
          make_float4(acc0[rg * 4 + 0], acc0[rg * 4 + 1], acc0[rg * 4 + 2], acc0[rg * 4 + 3]);
      *(float4*)(rowp + 32 + rg * 8 + hi * 4) =
          make_float4(acc1[rg * 4 + 0], acc1[rg * 4 + 1], acc1[rg * 4 + 2], acc1[rg * 4 + 3]);
    }
    if (l < 32) {
      const int q = q0 + w * 32 + l;
      *(float2*)&A.mlP[((size_t)(c * 16 + bh) * A.q_len + q) * 2] = make_float2(mrow, lrow);
    }
  } else {
    const float inv = 1.0f / lrow;
    const int b = bh >> 3, h = bh & 7;
    const size_t base = ((size_t)qrow * B_ + b) << 10;
#pragma unroll
    for (int hd = 0; hd < 2; ++hd)
#pragma unroll
      for (int rg = 0; rg < 4; ++rg) {
        const int col = h * 64 + hd * 32 + rg * 8 + hi * 4;
        ushort4 hv4, lv4;
#pragma unroll
        for (int i = 0; i < 4; ++i) {
          const float v = (hd ? acc1[rg * 4 + i] : acc0[rg * 4 + i]) * inv;
          const unsigned short hv = f2bf(v);
          ((unsigned short*)&hv4)[i] = hv;
          ((unsigned short*)&lv4)[i] = f2bf(v - bf2f(hv));
        }
        *(ushort4*)&A.OutP[base + col] = hv4;
        *(ushort4*)&A.OutP[base + 512 + col] = lv4;
      }
  }
}

// stage-1 launcher: grid (bh, q0blk, chunk)
__global__ __launch_bounds__(256, 2)
void flash_s1_kernel(FArgs a)
{
  flash_body(a, blockIdx.x, blockIdx.y, blockIdx.z);
}

// combined stage-3 + stage-2 launcher (flat 768-block grid):
__global__ __launch_bounds__(256, 2)
void flash_s23_kernel(FArgs a3, FArgs a2)
{
  const int bid = blockIdx.x;
  if (bid < 512) flash_body(a3, bid & 15, (bid >> 4) & 15, bid >> 8);
  else           flash_body(a2, bid & 15, ((bid - 512) >> 4) & 15, 0);
}

// ---------------------------------------------------------------------------
// Merge stage-1 partials (16 contiguous chunks) -> X2 pair + X2^T pair
// ---------------------------------------------------------------------------
__global__ __launch_bounds__(256)
void merge_x2_kernel(const float* __restrict__ acc, const float* __restrict__ ml,
                     unsigned short* __restrict__ X2hi, unsigned short* __restrict__ X2lo,
                     unsigned short* __restrict__ X2Thi, unsigned short* __restrict__ X2Tlo)
{
  const int idx = blockIdx.x * 256 + threadIdx.x;   // < 16*128*64
  const int d = idx & 63;
  const int q = (idx >> 6) & 127;
  const int bh = idx >> 13;
  float M = -INFINITY;
#pragma unroll
  for (int c = 0; c < 16; ++c)
    M = fmaxf(M, ml[((size_t)(c * 16 + bh) * 128 + q) * 2]);
  float ls = 0.f, o = 0.f;
#pragma unroll
  for (int c = 0; c < 16; ++c) {
    const size_t mi = ((size_t)(c * 16 + bh) * 128 + q) * 2;
    const float wgt = exp2f(ml[mi] - M);
    ls += wgt * ml[mi + 1];
    o += wgt * acc[(size_t)c * 131072 + ((size_t)bh * 128 + q) * 64 + d];
  }
  const float v = o / ls;
  const unsigned short hv = f2bf(v);
  const unsigned short lv = f2bf(v - bf2f(hv));
  X2hi[((size_t)bh * 128 + q) * 64 + d] = hv;
  X2lo[((size_t)bh * 128 + q) * 64 + d] = lv;
  const int qp = kvperm(q);
  X2Thi[((size_t)bh * 64 + d) * 128 + qp] = hv;
  X2Tlo[((size_t)bh * 64 + d) * 128 + qp] = lv;
}

// ---------------------------------------------------------------------------
// Merge stage-3 partials (2 chunks) -> packed pair rows [q*B+b][1024]
// ---------------------------------------------------------------------------
__global__ __launch_bounds__(256)
void merge_rows_kernel(const float* __restrict__ accA, const float* __restrict__ accB,
                       const float* __restrict__ ml, unsigned short* __restrict__ OutP)
{
  const int idx = blockIdx.x * 256 + threadIdx.x;   // < 16*2048*64
  const int d = idx & 63;
  const int q = (idx >> 6) & 2047;
  const int bh = idx >> 17;
  const size_t mi0 = ((size_t)bh * 2048 + q) * 2;
  const size_t mi1 = ((size_t)(16 + bh) * 2048 + q) * 2;
  const float m0 = ml[mi0], m1 = ml[mi1];
  const float M = fmaxf(m0, m1);
  const float w0 = exp2f(m0 - M), w1 = exp2f(m1 - M);
  const float ls = w0 * ml[mi0 + 1] + w1 * ml[mi1 + 1];
  const size_t aoff = ((size_t)bh * 2048 + q) * 64 + d;
  const float v = (w0 * accA[aoff] + w1 * accB[aoff]) / ls;
  const int b = bh >> 3, h = bh & 7;
  const size_t nrow = (size_t)q * B_ + b;
  const int col = h * 64 + d;
  const unsigned short hv = f2bf(v);
  OutP[nrow * 1024 + col] = hv;
  OutP[nrow * 1024 + 512 + col] = f2bf(v - bf2f(hv));
}

// ---------------------------------------------------------------------------
extern "C" void kernel_launch(void* const* d_in, const int* in_sizes, int n_in,
                              void* d_out, int out_size, void* d_ws, size_t ws_size,
                              hipStream_t stream)
{
  const float* reg_x = (const float*)d_in[0];
  const int*   ids   = (const int*)d_in[1];
  const float* table = (const float*)d_in[4];
  const float* wq1 = (const float*)d_in[5];  const float* bq1 = (const float*)d_in[6];
  const float* wq2 = (const float*)d_in[7];  const float* bq2 = (const float*)d_in[8];
  const float* wk  = (const float*)d_in[9];  const float* bk  = (const float*)d_in[10];
  const float* wv  = (const float*)d_in[11]; const float* bv  = (const float*)d_in[12];
  const float* wo  = (const float*)d_in[13]; const float* bo  = (const float*)d_in[14];
  const float* sgw = (const float*)d_in[15];
  const float* rgw = (const float*)d_in[16];
  const float* gb  = (const float*)d_in[17];
  float* out = (float*)d_out;
  char* W = (char*)d_ws;

  // ---- workspace layout (bytes), total 63,438,848 (< 66,060,288 proven-safe)
  // [R9/R11-proven layout]
  const size_t WSLOT  = 1572864;                  // 512*1536*2
  const size_t oApair = 0;                        //  8 MB [reuse: stage-1 acc, stage-3 accA]
  const size_t oW     = 8388608;                  //  7 x 1.5 MB
  const size_t oKhi   = oW + 7 * WSLOT;           // [reuse: attn_p over Khi+Klo]
  const size_t oKlo   = oKhi + 4194304;
  const size_t oVtHi  = oKlo + 4194304;
  const size_t oVtLo  = oVtHi + 4194304;
  const size_t oQ1hi  = oVtLo + 4194304;          // [reuse: sout_p over Q1hi+Q1lo]
  const size_t oQ1lo  = oQ1hi + 4194304;
  const size_t oQ2hi  = oQ1lo + 4194304;          // [reuse: rout_p over Q2hi+Q2lo]
  const size_t oQ2lo  = oQ2hi + 4194304;
  const size_t oAcc1  = oQ2lo + 4194304;          // 8 MB, stage-3 accB
  const size_t oSQhi  = oAcc1 + 8388608;
  const size_t oSQlo  = oSQhi + 262144;
  const size_t oX2hi  = oSQlo + 262144;
  const size_t oX2lo  = oX2hi + 262144;
  const size_t oX2Thi = oX2lo + 262144;
  const size_t oX2Tlo = oX2Thi + 262144;
  const size_t oMl    = oX2Tlo + 262144;          // +524,288

  auto U16 = [&](size_t off) { return (unsigned short*)(W + off); };
  auto F32 = [&](size_t off) { return (float*)(W + off); };
  unsigned short* Apair  = U16(oApair);
  unsigned short* Wk3    = U16(oW + 0 * WSLOT);
  unsigned short* Wv3    = U16(oW + 1 * WSLOT);
  unsigned short* Wq13   = U16(oW + 2 * WSLOT);
  unsigned short* Wq23   = U16(oW + 3 * WSLOT);
  unsigned short* Wsg3   = U16(oW + 4 * WSLOT);
  unsigned short* Wrg3   = U16(oW + 5 * WSLOT);
  unsigned short* Wo3    = U16(oW + 6 * WSLOT);
  float*          accS   = F32(oApair);           // stage-1 partials; stage-3 chunk 0
  float*          accB3  = F32(oAcc1);            // stage-3 chunk 1
  float*          mlP    = F32(oMl);
  unsigned short* sout_p = U16(oQ1hi);            // Q1 dead after stage-2 flash
  unsigned short* rout_p = U16(oQ2hi);            // Q2 dead after stage-3 flash
  unsigned short* attn_p = U16(oKhi);             // K dead after stage-3 flash

  const dim3 blk(256);

  // ---- fused precision splits + gather (1 launch)
  WSplit7 ws7;
  ws7.j[0] = WSplitJob{wk,  Wk3};
  ws7.j[1] = WSplitJob{wv,  Wv3};
  ws7.j[2] = WSplitJob{wq1, Wq13};
  ws7.j[3] = WSplitJob{wq2, Wq23};
  ws7.j[4] = WSplitJob{sgw, Wsg3};
  ws7.j[5] = WSplitJob{rgw, Wrg3};
  ws7.j[6] = WSplitJob{wo,  Wo3};
  fused_split_kernel<<<15872, blk, 0, stream>>>(reg_x, Apair, ws7, table, ids,
                                                U16(oSQhi), U16(oSQlo));

  // ---- 4 projections: m97-structure 128x128 gemm (512 blocks)
  GOuts4 proj;
  proj.o[0] = GOut{Wk3,  bk,  1.0f,    U16(oKhi),  U16(oKlo),  1};
  proj.o[1] = GOut{Wv3,  bv,  1.0f,    U16(oVtHi), U16(oVtLo), 2};
  proj.o[2] = GOut{Wq13, bq1, SLOG2E_, U16(oQ1hi), U16(oQ1lo), 1};
  proj.o[3] = GOut{Wq23, bq2, SLOG2E_, U16(oQ2hi), U16(oQ2lo), 1};
  gemm128_kernel<<<dim3(32, 4, 4), blk, 0, stream>>>(Apair, proj);

  // ---- stage 1: summary queries attend to reg tokens (16 KV chunks)
  FArgs a1;
  a1.Qhi = U16(oSQhi); a1.Qlo = U16(oSQlo);
  a1.Khi = U16(oKhi);  a1.Klo = U16(oKlo);
  a1.VtHi = U16(oVtHi); a1.VtLo = U16(oVtLo);
  a1.q_len = S_; a1.kv_len = R_; a1.chunk = 128; a1.zsplit = 16; a1.out_mode = 0;
  a1.accA = accS; a1.accB = accS; a1.mlP = mlP; a1.OutP = nullptr;
  flash_s1_kernel<<<dim3(16, 1, 16), blk, 0, stream>>>(a1);
  merge_x2_kernel<<<512, blk, 0, stream>>>(accS, mlP,
      U16(oX2hi), U16(oX2lo), U16(oX2Thi), U16(oX2Tlo));

  // ---- combined stage 3 (2 chunks, 512 blocks first) + stage 2 (256 blocks)
  FArgs a3;
  a3.Qhi = U16(oQ2hi); a3.Qlo = U16(oQ2lo);
  a3.Khi = U16(oKhi);  a3.Klo = U16(oKlo);
  a3.VtHi = U16(oVtHi); a3.VtLo = U16(oVtLo);
  a3.q_len = R_; a3.kv_len = R_; a3.chunk = 1024; a3.zsplit = 1; a3.out_mode = 0;
  a3.accA = accS; a3.accB = accB3; a3.mlP = mlP; a3.OutP = nullptr;
  FArgs a2;
  a2.Qhi = U16(oQ1hi); a2.Qlo = U16(oQ1lo);
  a2.Khi = U16(oX2hi); a2.Klo = U16(oX2lo);
  a2.VtHi = U16(oX2Thi); a2.VtLo = U16(oX2Tlo);
  a2.q_len = R_; a2.kv_len = S_; a2.chunk = 128; a2.zsplit = 1; a2.out_mode = 1;
  a2.accA = nullptr; a2.accB = nullptr; a2.mlP = mlP; a2.OutP = sout_p;
  flash_s23_kernel<<<768, blk, 0, stream>>>(a3, a2);

  // ---- merge stage-3 partials -> rout pair
  merge_rows_kernel<<<8192, blk, 0, stream>>>(accS, accB3, mlP, rout_p);

  // ---- fused gate GEMMs + sigmoid + blend -> attn pair
  gate_blend_gemm_kernel<<<dim3(32, 8), blk, 0, stream>>>(
      sout_p, rout_p, Wsg3, Wrg3, gb, attn_p);

  // ---- output projection -> d_out
  GemmOuts4 gf;
  gf.o[0].W = Wo3; gf.o[0].bias = bo; gf.o[0].scale = 1.0f; gf.o[0].Cf = out;
  gf.o[0].hi = nullptr; gf.o[0].lo = nullptr; gf.o[0].mode = 0;
  gf.o[1] = gf.o[0]; gf.o[2] = gf.o[0]; gf.o[3] = gf.o[0];
  gemm_split_kernel<<<dim3(32, 8, 1), blk, 0, stream>>>(attn_p, gf);
}

// Round 13
// 207.474 us; speedup vs baseline: 1.0721x; 1.0721x over previous
//
#include <hip/hip_runtime.h>
#include <cstdint>
#include <cstddef>

// Problem constants (fixed by setup_inputs)
constexpr int R_ = 2048;   // reg_len
constexpr int B_ = 2;      // batch
constexpr int S_ = 128;    // sum_len
constexpr int E_ = 512;    // embed dim
constexpr int H_ = 8;      // heads
constexpr int D_ = 64;     // head dim
constexpr int N_ = R_ * B_;            // 4096 token rows
constexpr float SCALE_ = 0.125f;       // D^-0.5
constexpr float LOG2E_ = 1.44269504088896340736f;
constexpr float SLOG2E_ = SCALE_ * LOG2E_;   // folded into Q scales (exp2 domain)

typedef short bf8_t __attribute__((ext_vector_type(8)));   // 8 bf16 in 4 VGPRs
typedef float f32x4 __attribute__((ext_vector_type(4)));
typedef float f32x16 __attribute__((ext_vector_type(16)));
typedef unsigned u32x4 __attribute__((ext_vector_type(4)));

#define MFMA16(a, b, c) __builtin_amdgcn_mfma_f32_16x16x32_bf16((a), (b), (c), 0, 0, 0)
#define MFMA32(a, b, c) __builtin_amdgcn_mfma_f32_32x32x16_bf16((a), (b), (c), 0, 0, 0)

__device__ __forceinline__ unsigned short f2bf(float f) {
  unsigned u = __builtin_bit_cast(unsigned, f);
  unsigned r = u + 0x7FFFu + ((u >> 16) & 1u);   // RNE
  return (unsigned short)(r >> 16);
}
__device__ __forceinline__ float bf2f(unsigned short h) {
  unsigned u = ((unsigned)h) << 16;
  return __builtin_bit_cast(float, u);
}
// kv-permutation (swap bits 2<->3 within each 16) for V^T storage; involution.
__device__ __forceinline__ int kvperm(int kv) {
  return (kv & ~15) | (kv & 3) | ((kv & 4) << 1) | ((kv & 8) >> 1);
}
// async global->LDS, 16B per lane (dst = wave-uniform base + lane*16)
__device__ __forceinline__ void gload16(const unsigned short* g, unsigned short* l) {
  __builtin_amdgcn_global_load_lds(
      (const __attribute__((address_space(1))) unsigned*)g,
      (__attribute__((address_space(3))) unsigned*)l, 16, 0, 0);
}

// ---------------------------------------------------------------------------
// Fused precision splits + gather (one launch)
// ---------------------------------------------------------------------------
struct WSplitJob { const float* src; unsigned short* dst; };
struct WSplit7 { WSplitJob j[7]; };

__global__ __launch_bounds__(256)
void fused_split_kernel(const float* __restrict__ reg_x, unsigned short* __restrict__ Apair,
                        WSplit7 P, const float* __restrict__ table,
                        const int* __restrict__ ids,
                        unsigned short* __restrict__ sqhi, unsigned short* __restrict__ sqlo)
{
  const int bx = blockIdx.x;
  const int tid = threadIdx.x;
  if (bx < 8192) {
    const int idx = bx * 256 + tid;                 // < 4096*512
    const int r = idx >> 9, c = idx & 511;
    const float v = reg_x[idx];
    const unsigned short hi = f2bf(v);
    unsigned short* d = Apair + ((size_t)r << 10) + c;
    d[0] = hi; d[512] = f2bf(v - bf2f(hi));
  } else if (bx < 15360) {
    const int bj = bx - 8192;
    const WSplitJob jb = P.j[bj >> 10];
    const int idx = (bj & 1023) * 256 + tid;        // < 512*512
    const int r = idx >> 9, c = idx & 511;
    const float v = jb.src[idx];
    const unsigned short hi = f2bf(v);
    const unsigned short lo = f2bf(v - bf2f(hi));
    unsigned short* d = jb.dst + (size_t)r * 1536 + c;
    d[0] = hi; d[512] = hi; d[1024] = lo;
  } else {
    const int idx = (bx - 15360) * 256 + tid;       // < B*H*S*D = 131072
    const int d = idx & 63;
    const int s = (idx >> 6) & 127;
    const int h = (idx >> 13) & 7;
    const int b = idx >> 16;
    const float v = table[(size_t)ids[b * S_ + s] * E_ + h * 64 + d] * SLOG2E_;
    const unsigned short hi = f2bf(v);
    sqhi[idx] = hi;
    sqlo[idx] = f2bf(v - bf2f(hi));
  }
}

// ---------------------------------------------------------------------------
// Split-precision MFMA GEMM (T14 reg-prefetch staging).  [R7-proven]
// Used for the final output GEMM.
// ---------------------------------------------------------------------------
struct GemmOut {
  const unsigned short* W;
  const float* bias;
  float scale;
  float* Cf;
  unsigned short* hi;
  unsigned short* lo;
  int mode;
};
struct GemmOuts4 { GemmOut o[4]; };

__global__ __launch_bounds__(256, 4)
void gemm_split_kernel(const unsigned short* __restrict__ A, GemmOuts4 P)
{
  const GemmOut g = P.o[blockIdx.z];
  __shared__ unsigned short As[128][48];
  __shared__ unsigned short Ws[64][48];

  const int tid = threadIdx.x;
  const int w = tid >> 6;          // wave 0..3
  const int l = tid & 63;
  const int lr = l & 15;
  const int lg = l >> 4;
  const int n0 = blockIdx.x * 128;
  const int o0 = blockIdx.y * 64;

  f32x4 acc[2][4];
#pragma unroll
  for (int m = 0; m < 2; ++m)
#pragma unroll
    for (int n = 0; n < 4; ++n) acc[m][n] = (f32x4){0.f, 0.f, 0.f, 0.f};

  const int ar = tid >> 1;          // 0..127
  const int ac = (tid & 1) * 16;
  const int wr = tid >> 2;          // 0..63
  const int wc = (tid & 3) * 8;

  bf8_t ra0 = *(const bf8_t*)(A + (size_t)(n0 + ar) * 1024 + ac);
  bf8_t ra1 = *(const bf8_t*)(A + (size_t)(n0 + ar) * 1024 + ac + 8);
  bf8_t rw0 = *(const bf8_t*)(g.W + (size_t)(o0 + wr) * 1536 + wc);

  for (int k0 = 0; k0 < 1536; k0 += 32) {
    __syncthreads();
    *(bf8_t*)&As[ar][ac] = ra0;
    *(bf8_t*)&As[ar][ac + 8] = ra1;
    *(bf8_t*)&Ws[wr][wc] = rw0;
    __syncthreads();
    if (k0 + 32 < 1536) {
      const int ak = (k0 + 32) & 1023;
      ra0 = *(const bf8_t*)(A + (size_t)(n0 + ar) * 1024 + ak + ac);
      ra1 = *(const bf8_t*)(A + (size_t)(n0 + ar) * 1024 + ak + ac + 8);
      rw0 = *(const bf8_t*)(g.W + (size_t)(o0 + wr) * 1536 + k0 + 32 + wc);
    }

    bf8_t bvs[4];
#pragma unroll
    for (int n = 0; n < 4; ++n)
      bvs[n] = *(const bf8_t*)&Ws[n * 16 + lr][lg * 8];
#pragma unroll
    for (int m = 0; m < 2; ++m) {
      bf8_t av = *(const bf8_t*)&As[w * 32 + m * 16 + lr][lg * 8];
#pragma unroll
      for (int n = 0; n < 4; ++n)
        acc[m][n] = MFMA16(av, bvs[n], acc[m][n]);
    }
  }

#pragma unroll
  for (int m = 0; m < 2; ++m)
#pragma unroll
    for (int n = 0; n < 4; ++n)
#pragma unroll
      for (int r = 0; r < 4; ++r) {
        const int row = n0 + w * 32 + m * 16 + lg * 4 + r;
        const int col = o0 + n * 16 + lr;
        float v = acc[m][n][r];
        if (g.bias) v += g.bias[col];
        v *= g.scale;
        if (g.mode == 0) {
          g.Cf[((size_t)row << 9) + col] = v;
        } else {
          const int bb = row & 1, rr = row >> 1;
          const int hh = col >> 6, dd = col & 63;
          size_t id;
          if (g.mode == 1) id = (((size_t)(bb * H_ + hh) * R_) + rr) * 64 + dd;
          else             id = (((size_t)(bb * H_ + hh) * 64) + dd) * R_ + kvperm(rr);
          const unsigned short hv = f2bf(v);
          g.hi[id] = hv;
          g.lo[id] = f2bf(v - bf2f(hv));
        }
      }
}

// ---------------------------------------------------------------------------
// m97-structure GEMM for the 4 projections.  [R12-proven]
// ---------------------------------------------------------------------------
struct GOut {
  const unsigned short* W;
  const float* bias;
  float scale;
  unsigned short* hi;
  unsigned short* lo;
  int mode;
};
struct GOuts4 { GOut o[4]; };

__global__ __launch_bounds__(256, 3)
void gemm128_kernel(const unsigned short* __restrict__ A, GOuts4 P)
{
  const GOut g = P.o[blockIdx.z];
  __shared__ unsigned short As[2][4096];   // 128 rows x 32 k, linear
  __shared__ unsigned short Ws[2][4096];

  const int tid = threadIdx.x;
  const int w = tid >> 6;
  const int l = tid & 63;
  const int lr = l & 15;
  const int lg = l >> 4;
  const int wr = (w >> 1) * 64;    // wave row base in tile
  const int wc = (w & 1) * 64;     // wave col base in tile
  const int n0 = blockIdx.x * 128;
  const int o0 = blockIdx.y * 128;

  const int srow = w * 32 + (l >> 2);
  const int scol = (l & 3) * 8;
  const unsigned short* A0 = A + (size_t)(n0 + srow) * 1024 + scol;
  const unsigned short* A1 = A0 + (size_t)16 * 1024;
  const unsigned short* W0 = g.W + (size_t)(o0 + srow) * 1536 + scol;
  const unsigned short* W1 = W0 + (size_t)16 * 1536;

  f32x4 acc[4][4];
#pragma unroll
  for (int m = 0; m < 4; ++m)
#pragma unroll
    for (int n = 0; n < 4; ++n) acc[m][n] = (f32x4){0.f, 0.f, 0.f, 0.f};

  gload16(A0, &As[0][w * 1024]);
  gload16(A1, &As[0][w * 1024 + 512]);
  gload16(W0, &Ws[0][w * 1024]);
  gload16(W1, &Ws[0][w * 1024 + 512]);
  __syncthreads();

  int buf = 0;
  for (int t = 0; t < 48; ++t) {
    if (t + 1 < 48) {
      const int ak = ((t + 1) * 32) & 1023;
      const int wk = (t + 1) * 32;
      gload16(A0 + ak, &As[buf ^ 1][w * 1024]);
      gload16(A1 + ak, &As[buf ^ 1][w * 1024 + 512]);
      gload16(W0 + wk, &Ws[buf ^ 1][w * 1024]);
      gload16(W1 + wk, &Ws[buf ^ 1][w * 1024 + 512]);
    }
    bf8_t av[4], bv[4];
#pragma unroll
    for (int m = 0; m < 4; ++m)
      av[m] = *(const bf8_t*)&As[buf][(wr + m * 16 + lr) * 32 + lg * 8];
#pragma unroll
    for (int n = 0; n < 4; ++n)
      bv[n] = *(const bf8_t*)&Ws[buf][(wc + n * 16 + lr) * 32 + lg * 8];
    __builtin_amdgcn_s_setprio(1);
#pragma unroll
    for (int m = 0; m < 4; ++m)
#pragma unroll
      for (int n = 0; n < 4; ++n)
        acc[m][n] = MFMA16(av[m], bv[n], acc[m][n]);
    __builtin_amdgcn_s_setprio(0);
    __syncthreads();
    buf ^= 1;
  }

#pragma unroll
  for (int m = 0; m < 4; ++m)
#pragma unroll
    for (int n = 0; n < 4; ++n)
#pragma unroll
      for (int r = 0; r < 4; ++r) {
        const int row = n0 + wr + m * 16 + lg * 4 + r;
        const int col = o0 + wc + n * 16 + lr;
        float v = acc[m][n][r];
        if (g.bias) v += g.bias[col];
        v *= g.scale;
        const int bb = row & 1, rr = row >> 1;
        const int hh = col >> 6, dd = col & 63;
        size_t id;
        if (g.mode == 1) id = (((size_t)(bb * H_ + hh) * R_) + rr) * 64 + dd;
        else             id = (((size_t)(bb * H_ + hh) * 64) + dd) * R_ + kvperm(rr);
        const unsigned short hv = f2bf(v);
        g.hi[id] = hv;
        g.lo[id] = f2bf(v - bf2f(hv));
      }
}

// ---------------------------------------------------------------------------
// Fused gate GEMMs + sigmoid + blend.  K reduced 1536->1024 per input:
// terms Ahi*Whi + Alo*Whi only (Ahi*Wlo dropped; sigmoid attenuates the
// resulting ~1e-3 logit error by g'(t)<=0.25).  64 K-steps total.
// ---------------------------------------------------------------------------
__global__ __launch_bounds__(256, 4)
void gate_blend_gemm_kernel(const unsigned short* __restrict__ A1,
                            const unsigned short* __restrict__ A2,
                            const unsigned short* __restrict__ W1,
                            const unsigned short* __restrict__ W2,
                            const float* __restrict__ gb,
                            unsigned short* __restrict__ attnP)
{
  __shared__ unsigned short As[128][48];
  __shared__ unsigned short Ws[64][48];

  const int tid = threadIdx.x;
  const int w = tid >> 6;
  const int l = tid & 63;
  const int lr = l & 15;
  const int lg = l >> 4;
  const int n0 = blockIdx.x * 128;
  const int o0 = blockIdx.y * 64;

  f32x4 acc[2][4];
#pragma unroll
  for (int m = 0; m < 2; ++m)
#pragma unroll
    for (int n = 0; n < 4; ++n) acc[m][n] = (f32x4){0.f, 0.f, 0.f, 0.f};

  const int ar = tid >> 1;
  const int ac = (tid & 1) * 16;
  const int wr = tid >> 2;
  const int wc = (tid & 3) * 8;

  // kk 0..31 -> input 1, kk 32..63 -> input 2; within each: k0 = (kk&31)*32
  // covers A cols 0..1023 (hi|lo) and W cols 0..1023 (hi|hi dup).
  auto aP = [&](int kk) {
    const unsigned short* Ax = (kk < 32) ? A1 : A2;
    const int k0 = (kk & 31) * 32;
    return Ax + (size_t)(n0 + ar) * 1024 + k0 + ac;
  };
  auto wP = [&](int kk) {
    const unsigned short* Wx = (kk < 32) ? W1 : W2;
    const int k0 = (kk & 31) * 32;
    return Wx + (size_t)(o0 + wr) * 1536 + k0 + wc;
  };

  bf8_t ra0 = *(const bf8_t*)aP(0);
  bf8_t ra1 = *(const bf8_t*)(aP(0) + 8);
  bf8_t rw0 = *(const bf8_t*)wP(0);

  for (int kk = 0; kk < 64; ++kk) {
    __syncthreads();
    *(bf8_t*)&As[ar][ac] = ra0;
    *(bf8_t*)&As[ar][ac + 8] = ra1;
    *(bf8_t*)&Ws[wr][wc] = rw0;
    __syncthreads();
    if (kk + 1 < 64) {
      ra0 = *(const bf8_t*)aP(kk + 1);
      ra1 = *(const bf8_t*)(aP(kk + 1) + 8);
      rw0 = *(const bf8_t*)wP(kk + 1);
    }

    bf8_t bvs[4];
#pragma unroll
    for (int n = 0; n < 4; ++n)
      bvs[n] = *(const bf8_t*)&Ws[n * 16 + lr][lg * 8];
#pragma unroll
    for (int m = 0; m < 2; ++m) {
      bf8_t av = *(const bf8_t*)&As[w * 32 + m * 16 + lr][lg * 8];
#pragma unroll
      for (int n = 0; n < 4; ++n)
        acc[m][n] = MFMA16(av, bvs[n], acc[m][n]);
    }
  }

#pragma unroll
  for (int m = 0; m < 2; ++m)
#pragma unroll
    for (int n = 0; n < 4; ++n)
#pragma unroll
      for (int r = 0; r < 4; ++r) {
        const int row = n0 + w * 32 + m * 16 + lg * 4 + r;
        const int col = o0 + n * 16 + lr;
        const float t = acc[m][n][r] + gb[col];
        const float gt = 1.0f / (1.0f + __expf(-t));
        const size_t base = (size_t)row << 10;
        const float so = bf2f(A1[base + col]) + bf2f(A1[base + 512 + col]);
        const float ro = bf2f(A2[base + col]) + bf2f(A2[base + 512 + col]);
        const float a = gt * so + (1.0f - gt) * ro;
        const unsigned short hv = f2bf(a);
        attnP[base + col] = hv;
        attnP[base + 512 + col] = f2bf(a - bf2f(hv));
      }
}

// ---------------------------------------------------------------------------
// Split-precision 32x32x16 flash attention body.  [R9/R11-proven]
// ---------------------------------------------------------------------------
struct FArgs {
  const unsigned short *Qhi, *Qlo, *Khi, *Klo, *VtHi, *VtLo;
  int q_len, kv_len, chunk, zsplit, out_mode;
  float *accA, *accB, *mlP;
  unsigned short* OutP;
};

__device__ __forceinline__
void flash_body(const FArgs& A, const int bh, const int q0blk, const int c)
{
  __shared__ unsigned short KsH[64][72];
  __shared__ unsigned short KsL[64][72];
  __shared__ unsigned short VsH[64][72];
  __shared__ unsigned short VsL[64][72];

  const int tid = threadIdx.x;
  const int w = tid >> 6;
  const int l = tid & 63;
  const int lq = l & 31;
  const int hi = l >> 5;
  const int q0 = q0blk * 128;
  const int kvbeg = c * A.chunk;
  const int kvend = kvbeg + A.chunk;
  const int qrow = q0 + w * 32 + lq;

  bf8_t qh[4], ql[4];
  {
    const size_t qbase = ((size_t)bh * A.q_len + qrow) * 64;
#pragma unroll
    for (int kd = 0; kd < 4; ++kd) {
      qh[kd] = *(const bf8_t*)(A.Qhi + qbase + kd * 16 + hi * 8);
      ql[kd] = *(const bf8_t*)(A.Qlo + qbase + kd * 16 + hi * 8);
    }
  }

  f32x16 acc0 = {0,0,0,0,0,0,0,0,0,0,0,0,0,0,0,0};
  f32x16 acc1 = {0,0,0,0,0,0,0,0,0,0,0,0,0,0,0,0};
  float mrow = -INFINITY;
  float lrow = 0.0f;

  const int sr = tid >> 2;            // staging row 0..63
  const int sc = (tid & 3) * 16;      // staging col

  bf8_t rkh[2], rkl[2], rvh[2], rvl[2];
  {
    const size_t kb = ((size_t)bh * A.kv_len + kvbeg + sr) * 64 + sc;
    rkh[0] = *(const bf8_t*)(A.Khi + kb);  rkh[1] = *(const bf8_t*)(A.Khi + kb + 8);
    rkl[0] = *(const bf8_t*)(A.Klo + kb);  rkl[1] = *(const bf8_t*)(A.Klo + kb + 8);
    const size_t vb = ((size_t)bh * 64 + sr) * A.kv_len + kvbeg + sc;
    rvh[0] = *(const bf8_t*)(A.VtHi + vb); rvh[1] = *(const bf8_t*)(A.VtHi + vb + 8);
    rvl[0] = *(const bf8_t*)(A.VtLo + vb); rvl[1] = *(const bf8_t*)(A.VtLo + vb + 8);
  }

  for (int kv0 = kvbeg; kv0 < kvend; kv0 += 64) {
    __syncthreads();
    *(bf8_t*)&KsH[sr][sc] = rkh[0];  *(bf8_t*)&KsH[sr][sc + 8] = rkh[1];
    *(bf8_t*)&KsL[sr][sc] = rkl[0];  *(bf8_t*)&KsL[sr][sc + 8] = rkl[1];
    *(bf8_t*)&VsH[sr][sc] = rvh[0];  *(bf8_t*)&VsH[sr][sc + 8] = rvh[1];
    *(bf8_t*)&VsL[sr][sc] = rvl[0];  *(bf8_t*)&VsL[sr][sc + 8] = rvl[1];
    __syncthreads();
    if (kv0 + 64 < kvend) {
      const size_t kb = ((size_t)bh * A.kv_len + kv0 + 64 + sr) * 64 + sc;
      rkh[0] = *(const bf8_t*)(A.Khi + kb);  rkh[1] = *(const bf8_t*)(A.Khi + kb + 8);
      rkl[0] = *(const bf8_t*)(A.Klo + kb);  rkl[1] = *(const bf8_t*)(A.Klo + kb + 8);
      const size_t vb = ((size_t)bh * 64 + sr) * A.kv_len + kv0 + 64 + sc;
      rvh[0] = *(const bf8_t*)(A.VtHi + vb); rvh[1] = *(const bf8_t*)(A.VtHi + vb + 8);
      rvl[0] = *(const bf8_t*)(A.VtLo + vb); rvl[1] = *(const bf8_t*)(A.VtLo + vb + 8);
    }

    // ---- QK^T swapped (24 MFMA32)
    f32x16 s0 = {0,0,0,0,0,0,0,0,0,0,0,0,0,0,0,0};
    f32x16 s1 = {0,0,0,0,0,0,0,0,0,0,0,0,0,0,0,0};
    __builtin_amdgcn_s_setprio(1);
#pragma unroll
    for (int kd = 0; kd < 4; ++kd) {
      const bf8_t kfh0 = *(const bf8_t*)&KsH[lq][kd * 16 + hi * 8];
      const bf8_t kfl0 = *(const bf8_t*)&KsL[lq][kd * 16 + hi * 8];
      s0 = MFMA32(kfh0, qh[kd], s0);
      s0 = MFMA32(kfh0, ql[kd], s0);
      s0 = MFMA32(kfl0, qh[kd], s0);
      const bf8_t kfh1 = *(const bf8_t*)&KsH[32 + lq][kd * 16 + hi * 8];
      const bf8_t kfl1 = *(const bf8_t*)&KsL[32 + lq][kd * 16 + hi * 8];
      s1 = MFMA32(kfh1, qh[kd], s1);
      s1 = MFMA32(kfh1, ql[kd], s1);
      s1 = MFMA32(kfl1, qh[kd], s1);
    }
    __builtin_amdgcn_s_setprio(0);

    // ---- online softmax (exp2 domain), defer-max (THR = 8)
    float mx = fmaxf(s0[0], s1[0]);
#pragma unroll
    for (int r = 1; r < 16; ++r) mx = fmaxf(mx, fmaxf(s0[r], s1[r]));
    mx = fmaxf(mx, __shfl_xor(mx, 32));
    if (mx > mrow + 8.0f) {
      const float f = exp2f(mrow - mx);
      mrow = mx;
      lrow *= f;
#pragma unroll
      for (int r = 0; r < 16; ++r) { acc0[r] *= f; acc1[r] *= f; }
    }
    float ts = 0.f;
#pragma unroll
    for (int r = 0; r < 16; ++r) { s0[r] = exp2f(s0[r] - mrow); ts += s0[r]; }
#pragma unroll
    for (int r = 0; r < 16; ++r) { s1[r] = exp2f(s1[r] - mrow); ts += s1[r]; }
    ts += __shfl_xor(ts, 32);
    lrow += ts;

    // ---- P pack: trunc hi + trunc lo via v_perm_b32 (lane-local)
    bf8_t pah[4], pal[4];
    const unsigned sel = 0x07060302u;
#pragma unroll
    for (int n = 0; n < 2; ++n)
#pragma unroll
      for (int ks = 0; ks < 2; ++ks) {
        u32x4 hp, lp;
#pragma unroll
        for (int p2 = 0; p2 < 4; ++p2) {
          const float a = n ? s1[ks * 8 + p2 * 2]     : s0[ks * 8 + p2 * 2];
          const float b = n ? s1[ks * 8 + p2 * 2 + 1] : s0[ks * 8 + p2 * 2 + 1];
          const unsigned ua = __builtin_bit_cast(unsigned, a);
          const unsigned ub = __builtin_bit_cast(unsigned, b);
          hp[p2] = __builtin_amdgcn_perm(ub, ua, sel);
          const float la = a - __builtin_bit_cast(float, ua & 0xFFFF0000u);
          const float lb = b - __builtin_bit_cast(float, ub & 0xFFFF0000u);
          lp[p2] = __builtin_amdgcn_perm(__builtin_bit_cast(unsigned, lb),
                                         __builtin_bit_cast(unsigned, la), sel);
        }
        pah[n * 2 + ks] = __builtin_bit_cast(bf8_t, hp);
        pal[n * 2 + ks] = __builtin_bit_cast(bf8_t, lp);
      }

    // ---- PV (24 MFMA32); V^T permuted-contiguous b128 reads
    __builtin_amdgcn_s_setprio(1);
#pragma unroll
    for (int n = 0; n < 2; ++n)
#pragma unroll
      for (int ks = 0; ks < 2; ++ks) {
        const int vcol = n * 32 + ks * 16 + hi * 8;
        const bf8_t ph = pah[n * 2 + ks];
        const bf8_t pl = pal[n * 2 + ks];
        {
          const bf8_t vfh = *(const bf8_t*)&VsH[lq][vcol];
          const bf8_t vfl = *(const bf8_t*)&VsL[lq][vcol];
          acc0 = MFMA32(vfh, ph, acc0);
          acc0 = MFMA32(vfh, pl, acc0);
          acc0 = MFMA32(vfl, ph, acc0);
        }
        {
          const bf8_t vfh = *(const bf8_t*)&VsH[32 + lq][vcol];
          const bf8_t vfl = *(const bf8_t*)&VsL[32 + lq][vcol];
          acc1 = MFMA32(vfh, ph, acc1);
          acc1 = MFMA32(vfh, pl, acc1);
          acc1 = MFMA32(vfl, ph, acc1);
        }
      }
    __builtin_amdgcn_s_setprio(0);
  }

  if (A.out_mode == 0) {
    const size_t cstride = (size_t)16 * A.q_len * 64;
    float* accbase = (c < A.zsplit) ? A.accA + (size_t)c * cstride
                                    : A.accB + (size_t)(c - A.zsplit) * cstride;
    float* rowp = accbase + ((size_t)bh * A.q_len + qrow) * 64;
#pragma unroll
    for (int rg = 0; rg < 4; ++rg) {
      *(float4*)(rowp + rg * 8 + hi * 4) =
          make_float4(acc0[rg * 4 + 0], acc0[rg * 4 + 1], acc0[rg * 4 + 2], acc0[rg * 4 + 3]);
      *(float4*)(rowp + 32 + rg * 8 + hi * 4) =
          make_float4(acc1[rg * 4 + 0], acc1[rg * 4 + 1], acc1[rg * 4 + 2], acc1[rg * 4 + 3]);
    }
    if (l < 32) {
      const int q = q0 + w * 32 + l;
      *(float2*)&A.mlP[((size_t)(c * 16 + bh) * A.q_len + q) * 2] = make_float2(mrow, lrow);
    }
  } else {
    const float inv = 1.0f / lrow;
    const int b = bh >> 3, h = bh & 7;
    const size_t base = ((size_t)qrow * B_ + b) << 10;
#pragma unroll
    for (int hd = 0; hd < 2; ++hd)
#pragma unroll
      for (int rg = 0; rg < 4; ++rg) {
        const int col = h * 64 + hd * 32 + rg * 8 + hi * 4;
        ushort4 hv4, lv4;
#pragma unroll
        for (int i = 0; i < 4; ++i) {
          const float v = (hd ? acc1[rg * 4 + i] : acc0[rg * 4 + i]) * inv;
          const unsigned short hv = f2bf(v);
          ((unsigned short*)&hv4)[i] = hv;
          ((unsigned short*)&lv4)[i] = f2bf(v - bf2f(hv));
        }
        *(ushort4*)&A.OutP[base + col] = hv4;
        *(ushort4*)&A.OutP[base + 512 + col] = lv4;
      }
  }
}

// stage-1 launcher: grid (bh, q0blk, chunk)
__global__ __launch_bounds__(256, 2)
void flash_s1_kernel(FArgs a)
{
  flash_body(a, blockIdx.x, blockIdx.y, blockIdx.z);
}

// combined stage-3 + stage-2 launcher (flat 768-block grid):
__global__ __launch_bounds__(256, 2)
void flash_s23_kernel(FArgs a3, FArgs a2)
{
  const int bid = blockIdx.x;
  if (bid < 512) flash_body(a3, bid & 15, (bid >> 4) & 15, bid >> 8);
  else           flash_body(a2, bid & 15, ((bid - 512) >> 4) & 15, 0);
}

// ---------------------------------------------------------------------------
// Merge stage-1 partials (16 contiguous chunks) -> X2 pair + X2^T pair
// ---------------------------------------------------------------------------
__global__ __launch_bounds__(256)
void merge_x2_kernel(const float* __restrict__ acc, const float* __restrict__ ml,
                     unsigned short* __restrict__ X2hi, unsigned short* __restrict__ X2lo,
                     unsigned short* __restrict__ X2Thi, unsigned short* __restrict__ X2Tlo)
{
  const int idx = blockIdx.x * 256 + threadIdx.x;   // < 16*128*64
  const int d = idx & 63;
  const int q = (idx >> 6) & 127;
  const int bh = idx >> 13;
  float M = -INFINITY;
#pragma unroll
  for (int c = 0; c < 16; ++c)
    M = fmaxf(M, ml[((size_t)(c * 16 + bh) * 128 + q) * 2]);
  float ls = 0.f, o = 0.f;
#pragma unroll
  for (int c = 0; c < 16; ++c) {
    const size_t mi = ((size_t)(c * 16 + bh) * 128 + q) * 2;
    const float wgt = exp2f(ml[mi] - M);
    ls += wgt * ml[mi + 1];
    o += wgt * acc[(size_t)c * 131072 + ((size_t)bh * 128 + q) * 64 + d];
  }
  const float v = o / ls;
  const unsigned short hv = f2bf(v);
  const unsigned short lv = f2bf(v - bf2f(hv));
  X2hi[((size_t)bh * 128 + q) * 64 + d] = hv;
  X2lo[((size_t)bh * 128 + q) * 64 + d] = lv;
  const int qp = kvperm(q);
  X2Thi[((size_t)bh * 64 + d) * 128 + qp] = hv;
  X2Tlo[((size_t)bh * 64 + d) * 128 + qp] = lv;
}

// ---------------------------------------------------------------------------
// Merge stage-3 partials (2 chunks) -> packed pair rows [q*B+b][1024]
// ---------------------------------------------------------------------------
__global__ __launch_bounds__(256)
void merge_rows_kernel(const float* __restrict__ accA, const float* __restrict__ accB,
                       const float* __restrict__ ml, unsigned short* __restrict__ OutP)
{
  const int idx = blockIdx.x * 256 + threadIdx.x;   // < 16*2048*64
  const int d = idx & 63;
  const int q = (idx >> 6) & 2047;
  const int bh = idx >> 17;
  const size_t mi0 = ((size_t)bh * 2048 + q) * 2;
  const size_t mi1 = ((size_t)(16 + bh) * 2048 + q) * 2;
  const float m0 = ml[mi0], m1 = ml[mi1];
  const float M = fmaxf(m0, m1);
  const float w0 = exp2f(m0 - M), w1 = exp2f(m1 - M);
  const float ls = w0 * ml[mi0 + 1] + w1 * ml[mi1 + 1];
  const size_t aoff = ((size_t)bh * 2048 + q) * 64 + d;
  const float v = (w0 * accA[aoff] + w1 * accB[aoff]) / ls;
  const int b = bh >> 3, h = bh & 7;
  const size_t nrow = (size_t)q * B_ + b;
  const int col = h * 64 + d;
  const unsigned short hv = f2bf(v);
  OutP[nrow * 1024 + col] = hv;
  OutP[nrow * 1024 + 512 + col] = f2bf(v - bf2f(hv));
}

// ---------------------------------------------------------------------------
extern "C" void kernel_launch(void* const* d_in, const int* in_sizes, int n_in,
                              void* d_out, int out_size, void* d_ws, size_t ws_size,
                              hipStream_t stream)
{
  const float* reg_x = (const float*)d_in[0];
  const int*   ids   = (const int*)d_in[1];
  const float* table = (const float*)d_in[4];
  const float* wq1 = (const float*)d_in[5];  const float* bq1 = (const float*)d_in[6];
  const float* wq2 = (const float*)d_in[7];  const float* bq2 = (const float*)d_in[8];
  const float* wk  = (const float*)d_in[9];  const float* bk  = (const float*)d_in[10];
  const float* wv  = (const float*)d_in[11]; const float* bv  = (const float*)d_in[12];
  const float* wo  = (const float*)d_in[13]; const float* bo  = (const float*)d_in[14];
  const float* sgw = (const float*)d_in[15];
  const float* rgw = (const float*)d_in[16];
  const float* gb  = (const float*)d_in[17];
  float* out = (float*)d_out;
  char* W = (char*)d_ws;

  // ---- workspace layout (bytes), total 63,438,848 (< 66,060,288 proven-safe)
  const size_t WSLOT  = 1572864;                  // 512*1536*2
  const size_t oApair = 0;                        //  8 MB [reuse: stage-1 acc, stage-3 accA]
  const size_t oW     = 8388608;                  //  7 x 1.5 MB
  const size_t oKhi   = oW + 7 * WSLOT;           // [reuse: attn_p over Khi+Klo]
  const size_t oKlo   = oKhi + 4194304;
  const size_t oVtHi  = oKlo + 4194304;
  const size_t oVtLo  = oVtHi + 4194304;
  const size_t oQ1hi  = oVtLo + 4194304;          // [reuse: sout_p over Q1hi+Q1lo]
  const size_t oQ1lo  = oQ1hi + 4194304;
  const size_t oQ2hi  = oQ1lo + 4194304;          // [reuse: rout_p over Q2hi+Q2lo]
  const size_t oQ2lo  = oQ2hi + 4194304;
  const size_t oAcc1  = oQ2lo + 4194304;          // 8 MB, stage-3 accB
  const size_t oSQhi  = oAcc1 + 8388608;
  const size_t oSQlo  = oSQhi + 262144;
  const size_t oX2hi  = oSQlo + 262144;
  const size_t oX2lo  = oX2hi + 262144;
  const size_t oX2Thi = oX2lo + 262144;
  const size_t oX2Tlo = oX2Thi + 262144;
  const size_t oMl    = oX2Tlo + 262144;          // +524,288

  auto U16 = [&](size_t off) { return (unsigned short*)(W + off); };
  auto F32 = [&](size_t off) { return (float*)(W + off); };
  unsigned short* Apair  = U16(oApair);
  unsigned short* Wk3    = U16(oW + 0 * WSLOT);
  unsigned short* Wv3    = U16(oW + 1 * WSLOT);
  unsigned short* Wq13   = U16(oW + 2 * WSLOT);
  unsigned short* Wq23   = U16(oW + 3 * WSLOT);
  unsigned short* Wsg3   = U16(oW + 4 * WSLOT);
  unsigned short* Wrg3   = U16(oW + 5 * WSLOT);
  unsigned short* Wo3    = U16(oW + 6 * WSLOT);
  float*          accS   = F32(oApair);           // stage-1 partials; stage-3 chunk 0
  float*          accB3  = F32(oAcc1);            // stage-3 chunk 1
  float*          mlP    = F32(oMl);
  unsigned short* sout_p = U16(oQ1hi);            // Q1 dead after stage-2 flash
  unsigned short* rout_p = U16(oQ2hi);            // Q2 dead after stage-3 flash
  unsigned short* attn_p = U16(oKhi);             // K dead after stage-3 flash

  const dim3 blk(256);

  // ---- fused precision splits + gather (1 launch)
  WSplit7 ws7;
  ws7.j[0] = WSplitJob{wk,  Wk3};
  ws7.j[1] = WSplitJob{wv,  Wv3};
  ws7.j[2] = WSplitJob{wq1, Wq13};
  ws7.j[3] = WSplitJob{wq2, Wq23};
  ws7.j[4] = WSplitJob{sgw, Wsg3};
  ws7.j[5] = WSplitJob{rgw, Wrg3};
  ws7.j[6] = WSplitJob{wo,  Wo3};
  fused_split_kernel<<<15872, blk, 0, stream>>>(reg_x, Apair, ws7, table, ids,
                                                U16(oSQhi), U16(oSQlo));

  // ---- 4 projections: m97-structure 128x128 gemm (512 blocks)
  GOuts4 proj;
  proj.o[0] = GOut{Wk3,  bk,  1.0f,    U16(oKhi),  U16(oKlo),  1};
  proj.o[1] = GOut{Wv3,  bv,  1.0f,    U16(oVtHi), U16(oVtLo), 2};
  proj.o[2] = GOut{Wq13, bq1, SLOG2E_, U16(oQ1hi), U16(oQ1lo), 1};
  proj.o[3] = GOut{Wq23, bq2, SLOG2E_, U16(oQ2hi), U16(oQ2lo), 1};
  gemm128_kernel<<<dim3(32, 4, 4), blk, 0, stream>>>(Apair, proj);

  // ---- stage 1: summary queries attend to reg tokens (16 KV chunks)
  FArgs a1;
  a1.Qhi = U16(oSQhi); a1.Qlo = U16(oSQlo);
  a1.Khi = U16(oKhi);  a1.Klo = U16(oKlo);
  a1.VtHi = U16(oVtHi); a1.VtLo = U16(oVtLo);
  a1.q_len = S_; a1.kv_len = R_; a1.chunk = 128; a1.zsplit = 16; a1.out_mode = 0;
  a1.accA = accS; a1.accB = accS; a1.mlP = mlP; a1.OutP = nullptr;
  flash_s1_kernel<<<dim3(16, 1, 16), blk, 0, stream>>>(a1);
  merge_x2_kernel<<<512, blk, 0, stream>>>(accS, mlP,
      U16(oX2hi), U16(oX2lo), U16(oX2Thi), U16(oX2Tlo));

  // ---- combined stage 3 (2 chunks, 512 blocks first) + stage 2 (256 blocks)
  FArgs a3;
  a3.Qhi = U16(oQ2hi); a3.Qlo = U16(oQ2lo);
  a3.Khi = U16(oKhi);  a3.Klo = U16(oKlo);
  a3.VtHi = U16(oVtHi); a3.VtLo = U16(oVtLo);
  a3.q_len = R_; a3.kv_len = R_; a3.chunk = 1024; a3.zsplit = 1; a3.out_mode = 0;
  a3.accA = accS; a3.accB = accB3; a3.mlP = mlP; a3.OutP = nullptr;
  FArgs a2;
  a2.Qhi = U16(oQ1hi); a2.Qlo = U16(oQ1lo);
  a2.Khi = U16(oX2hi); a2.Klo = U16(oX2lo);
  a2.VtHi = U16(oX2Thi); a2.VtLo = U16(oX2Tlo);
  a2.q_len = R_; a2.kv_len = S_; a2.chunk = 128; a2.zsplit = 1; a2.out_mode = 1;
  a2.accA = nullptr; a2.accB = nullptr; a2.mlP = mlP; a2.OutP = sout_p;
  flash_s23_kernel<<<768, blk, 0, stream>>>(a3, a2);

  // ---- merge stage-3 partials -> rout pair
  merge_rows_kernel<<<8192, blk, 0, stream>>>(accS, accB3, mlP, rout_p);

  // ---- fused gate GEMMs (K=1024 each) + sigmoid + blend -> attn pair
  gate_blend_gemm_kernel<<<dim3(32, 8), blk, 0, stream>>>(
      sout_p, rout_p, Wsg3, Wrg3, gb, attn_p);

  // ---- output projection -> d_out
  GemmOuts4 gf;
  gf.o[0].W = Wo3; gf.o[0].bias = bo; gf.o[0].scale = 1.0f; gf.o[0].Cf = out;
  gf.o[0].hi = nullptr; gf.o[0].lo = nullptr; gf.o[0].mode = 0;
  gf.o[1] = gf.o[0]; gf.o[2] = gf.o[0]; gf.o[3] = gf.o[0];
  gemm_split_kernel<<<dim3(32, 8, 1), blk, 0, stream>>>(attn_p, gf);
}

// Round 14
// 204.499 us; speedup vs baseline: 1.0877x; 1.0145x over previous
//
#include <hip/hip_runtime.h>
#include <cstdint>
#include <cstddef>

// Problem constants (fixed by setup_inputs)
constexpr int R_ = 2048;   // reg_len
constexpr int B_ = 2;      // batch
constexpr int S_ = 128;    // sum_len
constexpr int E_ = 512;    // embed dim
constexpr int H_ = 8;      // heads
constexpr int D_ = 64;     // head dim
constexpr int N_ = R_ * B_;            // 4096 token rows
constexpr float SCALE_ = 0.125f;       // D^-0.5
constexpr float LOG2E_ = 1.44269504088896340736f;
constexpr float SLOG2E_ = SCALE_ * LOG2E_;   // folded into Q scales (exp2 domain)

typedef short bf8_t __attribute__((ext_vector_type(8)));   // 8 bf16 in 4 VGPRs
typedef float f32x4 __attribute__((ext_vector_type(4)));
typedef float f32x16 __attribute__((ext_vector_type(16)));
typedef unsigned u32x4 __attribute__((ext_vector_type(4)));

#define MFMA16(a, b, c) __builtin_amdgcn_mfma_f32_16x16x32_bf16((a), (b), (c), 0, 0, 0)
#define MFMA32(a, b, c) __builtin_amdgcn_mfma_f32_32x32x16_bf16((a), (b), (c), 0, 0, 0)

__device__ __forceinline__ unsigned short f2bf(float f) {
  unsigned u = __builtin_bit_cast(unsigned, f);
  unsigned r = u + 0x7FFFu + ((u >> 16) & 1u);   // RNE
  return (unsigned short)(r >> 16);
}
__device__ __forceinline__ float bf2f(unsigned short h) {
  unsigned u = ((unsigned)h) << 16;
  return __builtin_bit_cast(float, u);
}
// kv-permutation (swap bits 2<->3 within each 16) for V^T storage; involution.
__device__ __forceinline__ int kvperm(int kv) {
  return (kv & ~15) | (kv & 3) | ((kv & 4) << 1) | ((kv & 8) >> 1);
}
// async global->LDS, 16B per lane (dst = wave-uniform base + lane*16)
__device__ __forceinline__ void gload16(const unsigned short* g, unsigned short* l) {
  __builtin_amdgcn_global_load_lds(
      (const __attribute__((address_space(1))) unsigned*)g,
      (__attribute__((address_space(3))) unsigned*)l, 16, 0, 0);
}
// split a float4 into hi (RNE bf16x4) and lo (RNE residual bf16x4)
__device__ __forceinline__ void split4(float4 v, ushort4& hi4, ushort4& lo4) {
  float vv[4] = {v.x, v.y, v.z, v.w};
#pragma unroll
  for (int j = 0; j < 4; ++j) {
    const unsigned short h = f2bf(vv[j]);
    ((unsigned short*)&hi4)[j] = h;
    ((unsigned short*)&lo4)[j] = f2bf(vv[j] - bf2f(h));
  }
}

// ---------------------------------------------------------------------------
// Fused precision splits + gather (one launch, vectorized float4/ushort4)
// blocks [0,2048): reg_x [4096][512] -> Apair [4096][1024] (hi|lo)
// blocks [2048,3840): 7 weights [512][512] -> [512][1536] (hi|hi|lo), 256/job
// blocks [3840,3968): summary-query gather+split (scale folded)
// ---------------------------------------------------------------------------
struct WSplitJob { const float* src; unsigned short* dst; };
struct WSplit7 { WSplitJob j[7]; };

__global__ __launch_bounds__(256)
void fused_split_kernel(const float* __restrict__ reg_x, unsigned short* __restrict__ Apair,
                        WSplit7 P, const float* __restrict__ table,
                        const int* __restrict__ ids,
                        unsigned short* __restrict__ sqhi, unsigned short* __restrict__ sqlo)
{
  const int bx = blockIdx.x;
  const int tid = threadIdx.x;
  if (bx < 2048) {
    const int base = (bx * 256 + tid) * 4;          // < 4096*512
    const int r = base >> 9, c = base & 511;
    const float4 v = *(const float4*)(reg_x + base);
    ushort4 hi4, lo4;
    split4(v, hi4, lo4);
    *(ushort4*)(Apair + ((size_t)r << 10) + c) = hi4;
    *(ushort4*)(Apair + ((size_t)r << 10) + 512 + c) = lo4;
  } else if (bx < 3840) {
    const int bj = bx - 2048;
    const WSplitJob jb = P.j[bj >> 8];
    const int base = ((bj & 255) * 256 + tid) * 4;  // < 512*512
    const int r = base >> 9, c = base & 511;
    const float4 v = *(const float4*)(jb.src + base);
    ushort4 hi4, lo4;
    split4(v, hi4, lo4);
    unsigned short* d = jb.dst + (size_t)r * 1536 + c;
    *(ushort4*)(d) = hi4;
    *(ushort4*)(d + 512) = hi4;
    *(ushort4*)(d + 1024) = lo4;
  } else {
    const int base = ((bx - 3840) * 256 + tid) * 4; // < B*H*S*D = 131072
    const int d = base & 63;
    const int s = (base >> 6) & 127;
    const int h = (base >> 13) & 7;
    const int b = base >> 16;
    float4 v = *(const float4*)(table + (size_t)ids[b * S_ + s] * E_ + h * 64 + d);
    v.x *= SLOG2E_; v.y *= SLOG2E_; v.z *= SLOG2E_; v.w *= SLOG2E_;
    ushort4 hi4, lo4;
    split4(v, hi4, lo4);
    *(ushort4*)(sqhi + base) = hi4;
    *(ushort4*)(sqlo + base) = lo4;
  }
}

// ---------------------------------------------------------------------------
// Split-precision MFMA GEMM (T14 reg-prefetch staging).  [R7-proven]
// Used for the final output GEMM.
// ---------------------------------------------------------------------------
struct GemmOut {
  const unsigned short* W;
  const float* bias;
  float scale;
  float* Cf;
  unsigned short* hi;
  unsigned short* lo;
  int mode;
};
struct GemmOuts4 { GemmOut o[4]; };

__global__ __launch_bounds__(256, 4)
void gemm_split_kernel(const unsigned short* __restrict__ A, GemmOuts4 P)
{
  const GemmOut g = P.o[blockIdx.z];
  __shared__ unsigned short As[128][48];
  __shared__ unsigned short Ws[64][48];

  const int tid = threadIdx.x;
  const int w = tid >> 6;          // wave 0..3
  const int l = tid & 63;
  const int lr = l & 15;
  const int lg = l >> 4;
  const int n0 = blockIdx.x * 128;
  const int o0 = blockIdx.y * 64;

  f32x4 acc[2][4];
#pragma unroll
  for (int m = 0; m < 2; ++m)
#pragma unroll
    for (int n = 0; n < 4; ++n) acc[m][n] = (f32x4){0.f, 0.f, 0.f, 0.f};

  const int ar = tid >> 1;          // 0..127
  const int ac = (tid & 1) * 16;
  const int wr = tid >> 2;          // 0..63
  const int wc = (tid & 3) * 8;

  bf8_t ra0 = *(const bf8_t*)(A + (size_t)(n0 + ar) * 1024 + ac);
  bf8_t ra1 = *(const bf8_t*)(A + (size_t)(n0 + ar) * 1024 + ac + 8);
  bf8_t rw0 = *(const bf8_t*)(g.W + (size_t)(o0 + wr) * 1536 + wc);

  for (int k0 = 0; k0 < 1536; k0 += 32) {
    __syncthreads();
    *(bf8_t*)&As[ar][ac] = ra0;
    *(bf8_t*)&As[ar][ac + 8] = ra1;
    *(bf8_t*)&Ws[wr][wc] = rw0;
    __syncthreads();
    if (k0 + 32 < 1536) {
      const int ak = (k0 + 32) & 1023;
      ra0 = *(const bf8_t*)(A + (size_t)(n0 + ar) * 1024 + ak + ac);
      ra1 = *(const bf8_t*)(A + (size_t)(n0 + ar) * 1024 + ak + ac + 8);
      rw0 = *(const bf8_t*)(g.W + (size_t)(o0 + wr) * 1536 + k0 + 32 + wc);
    }

    bf8_t bvs[4];
#pragma unroll
    for (int n = 0; n < 4; ++n)
      bvs[n] = *(const bf8_t*)&Ws[n * 16 + lr][lg * 8];
#pragma unroll
    for (int m = 0; m < 2; ++m) {
      bf8_t av = *(const bf8_t*)&As[w * 32 + m * 16 + lr][lg * 8];
#pragma unroll
      for (int n = 0; n < 4; ++n)
        acc[m][n] = MFMA16(av, bvs[n], acc[m][n]);
    }
  }

#pragma unroll
  for (int m = 0; m < 2; ++m)
#pragma unroll
    for (int n = 0; n < 4; ++n)
#pragma unroll
      for (int r = 0; r < 4; ++r) {
        const int row = n0 + w * 32 + m * 16 + lg * 4 + r;
        const int col = o0 + n * 16 + lr;
        float v = acc[m][n][r];
        if (g.bias) v += g.bias[col];
        v *= g.scale;
        if (g.mode == 0) {
          g.Cf[((size_t)row << 9) + col] = v;
        } else {
          const int bb = row & 1, rr = row >> 1;
          const int hh = col >> 6, dd = col & 63;
          size_t id;
          if (g.mode == 1) id = (((size_t)(bb * H_ + hh) * R_) + rr) * 64 + dd;
          else             id = (((size_t)(bb * H_ + hh) * 64) + dd) * R_ + kvperm(rr);
          const unsigned short hv = f2bf(v);
          g.hi[id] = hv;
          g.lo[id] = f2bf(v - bf2f(hv));
        }
      }
}

// ---------------------------------------------------------------------------
// m97-structure GEMM for the 4 projections.  [R12-proven]
// ---------------------------------------------------------------------------
struct GOut {
  const unsigned short* W;
  const float* bias;
  float scale;
  unsigned short* hi;
  unsigned short* lo;
  int mode;
};
struct GOuts4 { GOut o[4]; };

__global__ __launch_bounds__(256, 3)
void gemm128_kernel(const unsigned short* __restrict__ A, GOuts4 P)
{
  const GOut g = P.o[blockIdx.z];
  __shared__ unsigned short As[2][4096];   // 128 rows x 32 k, linear
  __shared__ unsigned short Ws[2][4096];

  const int tid = threadIdx.x;
  const int w = tid >> 6;
  const int l = tid & 63;
  const int lr = l & 15;
  const int lg = l >> 4;
  const int wr = (w >> 1) * 64;    // wave row base in tile
  const int wc = (w & 1) * 64;     // wave col base in tile
  const int n0 = blockIdx.x * 128;
  const int o0 = blockIdx.y * 128;

  const int srow = w * 32 + (l >> 2);
  const int scol = (l & 3) * 8;
  const unsigned short* A0 = A + (size_t)(n0 + srow) * 1024 + scol;
  const unsigned short* A1 = A0 + (size_t)16 * 1024;
  const unsigned short* W0 = g.W + (size_t)(o0 + srow) * 1536 + scol;
  const unsigned short* W1 = W0 + (size_t)16 * 1536;

  f32x4 acc[4][4];
#pragma unroll
  for (int m = 0; m < 4; ++m)
#pragma unroll
    for (int n = 0; n < 4; ++n) acc[m][n] = (f32x4){0.f, 0.f, 0.f, 0.f};

  gload16(A0, &As[0][w * 1024]);
  gload16(A1, &As[0][w * 1024 + 512]);
  gload16(W0, &Ws[0][w * 1024]);
  gload16(W1, &Ws[0][w * 1024 + 512]);
  __syncthreads();

  int buf = 0;
  for (int t = 0; t < 48; ++t) {
    if (t + 1 < 48) {
      const int ak = ((t + 1) * 32) & 1023;
      const int wk = (t + 1) * 32;
      gload16(A0 + ak, &As[buf ^ 1][w * 1024]);
      gload16(A1 + ak, &As[buf ^ 1][w * 1024 + 512]);
      gload16(W0 + wk, &Ws[buf ^ 1][w * 1024]);
      gload16(W1 + wk, &Ws[buf ^ 1][w * 1024 + 512]);
    }
    bf8_t av[4], bv[4];
#pragma unroll
    for (int m = 0; m < 4; ++m)
      av[m] = *(const bf8_t*)&As[buf][(wr + m * 16 + lr) * 32 + lg * 8];
#pragma unroll
    for (int n = 0; n < 4; ++n)
      bv[n] = *(const bf8_t*)&Ws[buf][(wc + n * 16 + lr) * 32 + lg * 8];
    __builtin_amdgcn_s_setprio(1);
#pragma unroll
    for (int m = 0; m < 4; ++m)
#pragma unroll
      for (int n = 0; n < 4; ++n)
        acc[m][n] = MFMA16(av[m], bv[n], acc[m][n]);
    __builtin_amdgcn_s_setprio(0);
    __syncthreads();
    buf ^= 1;
  }

#pragma unroll
  for (int m = 0; m < 4; ++m)
#pragma unroll
    for (int n = 0; n < 4; ++n)
#pragma unroll
      for (int r = 0; r < 4; ++r) {
        const int row = n0 + wr + m * 16 + lg * 4 + r;
        const int col = o0 + wc + n * 16 + lr;
        float v = acc[m][n][r];
        if (g.bias) v += g.bias[col];
        v *= g.scale;
        const int bb = row & 1, rr = row >> 1;
        const int hh = col >> 6, dd = col & 63;
        size_t id;
        if (g.mode == 1) id = (((size_t)(bb * H_ + hh) * R_) + rr) * 64 + dd;
        else             id = (((size_t)(bb * H_ + hh) * 64) + dd) * R_ + kvperm(rr);
        const unsigned short hv = f2bf(v);
        g.hi[id] = hv;
        g.lo[id] = f2bf(v - bf2f(hv));
      }
}

// ---------------------------------------------------------------------------
// Fused gate GEMMs + sigmoid + blend.  [R13-proven, K=1024 per input]
// ---------------------------------------------------------------------------
__global__ __launch_bounds__(256, 4)
void gate_blend_gemm_kernel(const unsigned short* __restrict__ A1,
                            const unsigned short* __restrict__ A2,
                            const unsigned short* __restrict__ W1,
                            const unsigned short* __restrict__ W2,
                            const float* __restrict__ gb,
                            unsigned short* __restrict__ attnP)
{
  __shared__ unsigned short As[128][48];
  __shared__ unsigned short Ws[64][48];

  const int tid = threadIdx.x;
  const int w = tid >> 6;
  const int l = tid & 63;
  const int lr = l & 15;
  const int lg = l >> 4;
  const int n0 = blockIdx.x * 128;
  const int o0 = blockIdx.y * 64;

  f32x4 acc[2][4];
#pragma unroll
  for (int m = 0; m < 2; ++m)
#pragma unroll
    for (int n = 0; n < 4; ++n) acc[m][n] = (f32x4){0.f, 0.f, 0.f, 0.f};

  const int ar = tid >> 1;
  const int ac = (tid & 1) * 16;
  const int wr = tid >> 2;
  const int wc = (tid & 3) * 8;

  auto aP = [&](int kk) {
    const unsigned short* Ax = (kk < 32) ? A1 : A2;
    const int k0 = (kk & 31) * 32;
    return Ax + (size_t)(n0 + ar) * 1024 + k0 + ac;
  };
  auto wP = [&](int kk) {
    const unsigned short* Wx = (kk < 32) ? W1 : W2;
    const int k0 = (kk & 31) * 32;
    return Wx + (size_t)(o0 + wr) * 1536 + k0 + wc;
  };

  bf8_t ra0 = *(const bf8_t*)aP(0);
  bf8_t ra1 = *(const bf8_t*)(aP(0) + 8);
  bf8_t rw0 = *(const bf8_t*)wP(0);

  for (int kk = 0; kk < 64; ++kk) {
    __syncthreads();
    *(bf8_t*)&As[ar][ac] = ra0;
    *(bf8_t*)&As[ar][ac + 8] = ra1;
    *(bf8_t*)&Ws[wr][wc] = rw0;
    __syncthreads();
    if (kk + 1 < 64) {
      ra0 = *(const bf8_t*)aP(kk + 1);
      ra1 = *(const bf8_t*)(aP(kk + 1) + 8);
      rw0 = *(const bf8_t*)wP(kk + 1);
    }

    bf8_t bvs[4];
#pragma unroll
    for (int n = 0; n < 4; ++n)
      bvs[n] = *(const bf8_t*)&Ws[n * 16 + lr][lg * 8];
#pragma unroll
    for (int m = 0; m < 2; ++m) {
      bf8_t av = *(const bf8_t*)&As[w * 32 + m * 16 + lr][lg * 8];
#pragma unroll
      for (int n = 0; n < 4; ++n)
        acc[m][n] = MFMA16(av, bvs[n], acc[m][n]);
    }
  }

#pragma unroll
  for (int m = 0; m < 2; ++m)
#pragma unroll
    for (int n = 0; n < 4; ++n)
#pragma unroll
      for (int r = 0; r < 4; ++r) {
        const int row = n0 + w * 32 + m * 16 + lg * 4 + r;
        const int col = o0 + n * 16 + lr;
        const float t = acc[m][n][r] + gb[col];
        const float gt = 1.0f / (1.0f + __expf(-t));
        const size_t base = (size_t)row << 10;
        const float so = bf2f(A1[base + col]) + bf2f(A1[base + 512 + col]);
        const float ro = bf2f(A2[base + col]) + bf2f(A2[base + 512 + col]);
        const float a = gt * so + (1.0f - gt) * ro;
        const unsigned short hv = f2bf(a);
        attnP[base + col] = hv;
        attnP[base + 512 + col] = f2bf(a - bf2f(hv));
      }
}

// ---------------------------------------------------------------------------
// Split-precision 32x32x16 flash attention body.  [R9/R11-proven]
// ---------------------------------------------------------------------------
struct FArgs {
  const unsigned short *Qhi, *Qlo, *Khi, *Klo, *VtHi, *VtLo;
  int q_len, kv_len, chunk, zsplit, out_mode;
  float *accA, *accB, *mlP;
  unsigned short* OutP;
};

__device__ __forceinline__
void flash_body(const FArgs& A, const int bh, const int q0blk, const int c)
{
  __shared__ unsigned short KsH[64][72];
  __shared__ unsigned short KsL[64][72];
  __shared__ unsigned short VsH[64][72];
  __shared__ unsigned short VsL[64][72];

  const int tid = threadIdx.x;
  const int w = tid >> 6;
  const int l = tid & 63;
  const int lq = l & 31;
  const int hi = l >> 5;
  const int q0 = q0blk * 128;
  const int kvbeg = c * A.chunk;
  const int kvend = kvbeg + A.chunk;
  const int qrow = q0 + w * 32 + lq;

  bf8_t qh[4], ql[4];
  {
    const size_t qbase = ((size_t)bh * A.q_len + qrow) * 64;
#pragma unroll
    for (int kd = 0; kd < 4; ++kd) {
      qh[kd] = *(const bf8_t*)(A.Qhi + qbase + kd * 16 + hi * 8);
      ql[kd] = *(const bf8_t*)(A.Qlo + qbase + kd * 16 + hi * 8);
    }
  }

  f32x16 acc0 = {0,0,0,0,0,0,0,0,0,0,0,0,0,0,0,0};
  f32x16 acc1 = {0,0,0,0,0,0,0,0,0,0,0,0,0,0,0,0};
  float mrow = -INFINITY;
  float lrow = 0.0f;

  const int sr = tid >> 2;            // staging row 0..63
  const int sc = (tid & 3) * 16;      // staging col

  bf8_t rkh[2], rkl[2], rvh[2], rvl[2];
  {
    const size_t kb = ((size_t)bh * A.kv_len + kvbeg + sr) * 64 + sc;
    rkh[0] = *(const bf8_t*)(A.Khi + kb);  rkh[1] = *(const bf8_t*)(A.Khi + kb + 8);
    rkl[0] = *(const bf8_t*)(A.Klo + kb);  rkl[1] = *(const bf8_t*)(A.Klo + kb + 8);
    const size_t vb = ((size_t)bh * 64 + sr) * A.kv_len + kvbeg + sc;
    rvh[0] = *(const bf8_t*)(A.VtHi + vb); rvh[1] = *(const bf8_t*)(A.VtHi + vb + 8);
    rvl[0] = *(const bf8_t*)(A.VtLo + vb); rvl[1] = *(const bf8_t*)(A.VtLo + vb + 8);
  }

  for (int kv0 = kvbeg; kv0 < kvend; kv0 += 64) {
    __syncthreads();
    *(bf8_t*)&KsH[sr][sc] = rkh[0];  *(bf8_t*)&KsH[sr][sc + 8] = rkh[1];
    *(bf8_t*)&KsL[sr][sc] = rkl[0];  *(bf8_t*)&KsL[sr][sc + 8] = rkl[1];
    *(bf8_t*)&VsH[sr][sc] = rvh[0];  *(bf8_t*)&VsH[sr][sc + 8] = rvh[1];
    *(bf8_t*)&VsL[sr][sc] = rvl[0];  *(bf8_t*)&VsL[sr][sc + 8] = rvl[1];
    __syncthreads();
    if (kv0 + 64 < kvend) {
      const size_t kb = ((size_t)bh * A.kv_len + kv0 + 64 + sr) * 64 + sc;
      rkh[0] = *(const bf8_t*)(A.Khi + kb);  rkh[1] = *(const bf8_t*)(A.Khi + kb + 8);
      rkl[0] = *(const bf8_t*)(A.Klo + kb);  rkl[1] = *(const bf8_t*)(A.Klo + kb + 8);
      const size_t vb = ((size_t)bh * 64 + sr) * A.kv_len + kv0 + 64 + sc;
      rvh[0] = *(const bf8_t*)(A.VtHi + vb); rvh[1] = *(const bf8_t*)(A.VtHi + vb + 8);
      rvl[0] = *(const bf8_t*)(A.VtLo + vb); rvl[1] = *(const bf8_t*)(A.VtLo + vb + 8);
    }

    // ---- QK^T swapped (24 MFMA32)
    f32x16 s0 = {0,0,0,0,0,0,0,0,0,0,0,0,0,0,0,0};
    f32x16 s1 = {0,0,0,0,0,0,0,0,0,0,0,0,0,0,0,0};
    __builtin_amdgcn_s_setprio(1);
#pragma unroll
    for (int kd = 0; kd < 4; ++kd) {
      const bf8_t kfh0 = *(const bf8_t*)&KsH[lq][kd * 16 + hi * 8];
      const bf8_t kfl0 = *(const bf8_t*)&KsL[lq][kd * 16 + hi * 8];
      s0 = MFMA32(kfh0, qh[kd], s0);
      s0 = MFMA32(kfh0, ql[kd], s0);
      s0 = MFMA32(kfl0, qh[kd], s0);
      const bf8_t kfh1 = *(const bf8_t*)&KsH[32 + lq][kd * 16 + hi * 8];
      const bf8_t kfl1 = *(const bf8_t*)&KsL[32 + lq][kd * 16 + hi * 8];
      s1 = MFMA32(kfh1, qh[kd], s1);
      s1 = MFMA32(kfh1, ql[kd], s1);
      s1 = MFMA32(kfl1, qh[kd], s1);
    }
    __builtin_amdgcn_s_setprio(0);

    // ---- online softmax (exp2 domain), defer-max (THR = 8)
    float mx = fmaxf(s0[0], s1[0]);
#pragma unroll
    for (int r = 1; r < 16; ++r) mx = fmaxf(mx, fmaxf(s0[r], s1[r]));
    mx = fmaxf(mx, __shfl_xor(mx, 32));
    if (mx > mrow + 8.0f) {
      const float f = exp2f(mrow - mx);
      mrow = mx;
      lrow *= f;
#pragma unroll
      for (int r = 0; r < 16; ++r) { acc0[r] *= f; acc1[r] *= f; }
    }
    float ts = 0.f;
#pragma unroll
    for (int r = 0; r < 16; ++r) { s0[r] = exp2f(s0[r] - mrow); ts += s0[r]; }
#pragma unroll
    for (int r = 0; r < 16; ++r) { s1[r] = exp2f(s1[r] - mrow); ts += s1[r]; }
    ts += __shfl_xor(ts, 32);
    lrow += ts;

    // ---- P pack: trunc hi + trunc lo via v_perm_b32 (lane-local)
    bf8_t pah[4], pal[4];
    const unsigned sel = 0x07060302u;
#pragma unroll
    for (int n = 0; n < 2; ++n)
#pragma unroll
      for (int ks = 0; ks < 2; ++ks) {
        u32x4 hp, lp;
#pragma unroll
        for (int p2 = 0; p2 < 4; ++p2) {
          const float a = n ? s1[ks * 8 + p2 * 2]     : s0[ks * 8 + p2 * 2];
          const float b = n ? s1[ks * 8 + p2 * 2 + 1] : s0[ks * 8 + p2 * 2 + 1];
          const unsigned ua = __builtin_bit_cast(unsigned, a);
          const unsigned ub = __builtin_bit_cast(unsigned, b);
          hp[p2] = __builtin_amdgcn_perm(ub, ua, sel);
          const float la = a - __builtin_bit_cast(float, ua & 0xFFFF0000u);
          const float lb = b - __builtin_bit_cast(float, ub & 0xFFFF0000u);
          lp[p2] = __builtin_amdgcn_perm(__builtin_bit_cast(unsigned, lb),
                                         __builtin_bit_cast(unsigned, la), sel);
        }
        pah[n * 2 + ks] = __builtin_bit_cast(bf8_t, hp);
        pal[n * 2 + ks] = __builtin_bit_cast(bf8_t, lp);
      }

    // ---- PV (24 MFMA32); V^T permuted-contiguous b128 reads
    __builtin_amdgcn_s_setprio(1);
#pragma unroll
    for (int n = 0; n < 2; ++n)
#pragma unroll
      for (int ks = 0; ks < 2; ++ks) {
        const int vcol = n * 32 + ks * 16 + hi * 8;
        const bf8_t ph = pah[n * 2 + ks];
        const bf8_t pl = pal[n * 2 + ks];
        {
          const bf8_t vfh = *(const bf8_t*)&VsH[lq][vcol];
          const bf8_t vfl = *(const bf8_t*)&VsL[lq][vcol];
          acc0 = MFMA32(vfh, ph, acc0);
          acc0 = MFMA32(vfh, pl, acc0);
          acc0 = MFMA32(vfl, ph, acc0);
        }
        {
          const bf8_t vfh = *(const bf8_t*)&VsH[32 + lq][vcol];
          const bf8_t vfl = *(const bf8_t*)&VsL[32 + lq][vcol];
          acc1 = MFMA32(vfh, ph, acc1);
          acc1 = MFMA32(vfh, pl, acc1);
          acc1 = MFMA32(vfl, ph, acc1);
        }
      }
    __builtin_amdgcn_s_setprio(0);
  }

  if (A.out_mode == 0) {
    const size_t cstride = (size_t)16 * A.q_len * 64;
    float* accbase = (c < A.zsplit) ? A.accA + (size_t)c * cstride
                                    : A.accB + (size_t)(c - A.zsplit) * cstride;
    float* rowp = accbase + ((size_t)bh * A.q_len + qrow) * 64;
#pragma unroll
    for (int rg = 0; rg < 4; ++rg) {
      *(float4*)(rowp + rg * 8 + hi * 4) =
          make_float4(acc0[rg * 4 + 0], acc0[rg * 4 + 1], acc0[rg * 4 + 2], acc0[rg * 4 + 3]);
      *(float4*)(rowp + 32 + rg * 8 + hi * 4) =
          make_float4(acc1[rg * 4 + 0], acc1[rg * 4 + 1], acc1[rg * 4 + 2], acc1[rg * 4 + 3]);
    }
    if (l < 32) {
      const int q = q0 + w * 32 + l;
      *(float2*)&A.mlP[((size_t)(c * 16 + bh) * A.q_len + q) * 2] = make_float2(mrow, lrow);
    }
  } else {
    const float inv = 1.0f / lrow;
    const int b = bh >> 3, h = bh & 7;
    const size_t base = ((size_t)qrow * B_ + b) << 10;
#pragma unroll
    for (int hd = 0; hd < 2; ++hd)
#pragma unroll
      for (int rg = 0; rg < 4; ++rg) {
        const int col = h * 64 + hd * 32 + rg * 8 + hi * 4;
        ushort4 hv4, lv4;
#pragma unroll
        for (int i = 0; i < 4; ++i) {
          const float v = (hd ? acc1[rg * 4 + i] : acc0[rg * 4 + i]) * inv;
          const unsigned short hv = f2bf(v);
          ((unsigned short*)&hv4)[i] = hv;
          ((unsigned short*)&lv4)[i] = f2bf(v - bf2f(hv));
        }
        *(ushort4*)&A.OutP[base + col] = hv4;
        *(ushort4*)&A.OutP[base + 512 + col] = lv4;
      }
  }
}

// stage-1 launcher: grid (bh, q0blk, chunk)
__global__ __launch_bounds__(256, 2)
void flash_s1_kernel(FArgs a)
{
  flash_body(a, blockIdx.x, blockIdx.y, blockIdx.z);
}

// combined stage-3 + stage-2 launcher (flat 768-block grid):
__global__ __launch_bounds__(256, 2)
void flash_s23_kernel(FArgs a3, FArgs a2)
{
  const int bid = blockIdx.x;
  if (bid < 512) flash_body(a3, bid & 15, (bid >> 4) & 15, bid >> 8);
  else           flash_body(a2, bid & 15, ((bid - 512) >> 4) & 15, 0);
}

// ---------------------------------------------------------------------------
// Merge stage-1 partials -> X2 pair + X2^T pair (vectorized, 4 d per thread)
// ---------------------------------------------------------------------------
__global__ __launch_bounds__(256)
void merge_x2_kernel(const float* __restrict__ acc, const float* __restrict__ ml,
                     unsigned short* __restrict__ X2hi, unsigned short* __restrict__ X2lo,
                     unsigned short* __restrict__ X2Thi, unsigned short* __restrict__ X2Tlo)
{
  const int base = (blockIdx.x * 256 + threadIdx.x) * 4;   // < 16*128*64
  const int d = base & 63;
  const int q = (base >> 6) & 127;
  const int bh = base >> 13;
  float M = -INFINITY;
#pragma unroll
  for (int c = 0; c < 16; ++c)
    M = fmaxf(M, ml[((size_t)(c * 16 + bh) * 128 + q) * 2]);
  float ls = 0.f;
  float4 o = make_float4(0.f, 0.f, 0.f, 0.f);
#pragma unroll
  for (int c = 0; c < 16; ++c) {
    const size_t mi = ((size_t)(c * 16 + bh) * 128 + q) * 2;
    const float wgt = exp2f(ml[mi] - M);
    ls += wgt * ml[mi + 1];
    const float4 a = *(const float4*)&acc[(size_t)c * 131072 + ((size_t)bh * 128 + q) * 64 + d];
    o.x += wgt * a.x; o.y += wgt * a.y; o.z += wgt * a.z; o.w += wgt * a.w;
  }
  const float inv = 1.0f / ls;
  float4 v = make_float4(o.x * inv, o.y * inv, o.z * inv, o.w * inv);
  ushort4 hv4, lv4;
  split4(v, hv4, lv4);
  *(ushort4*)&X2hi[((size_t)bh * 128 + q) * 64 + d] = hv4;
  *(ushort4*)&X2lo[((size_t)bh * 128 + q) * 64 + d] = lv4;
  const int qp = kvperm(q);
#pragma unroll
  for (int j = 0; j < 4; ++j) {
    X2Thi[((size_t)bh * 64 + d + j) * 128 + qp] = ((unsigned short*)&hv4)[j];
    X2Tlo[((size_t)bh * 64 + d + j) * 128 + qp] = ((unsigned short*)&lv4)[j];
  }
}

// ---------------------------------------------------------------------------
// Merge stage-3 partials (2 chunks) -> packed pair rows (vectorized, 4/thread)
// ---------------------------------------------------------------------------
__global__ __launch_bounds__(256)
void merge_rows_kernel(const float* __restrict__ accA, const float* __restrict__ accB,
                       const float* __restrict__ ml, unsigned short* __restrict__ OutP)
{
  const int base = (blockIdx.x * 256 + threadIdx.x) * 4;   // < 16*2048*64
  const int d = base & 63;
  const int q = (base >> 6) & 2047;
  const int bh = base >> 17;
  const size_t mi0 = ((size_t)bh * 2048 + q) * 2;
  const size_t mi1 = ((size_t)(16 + bh) * 2048 + q) * 2;
  const float m0 = ml[mi0], m1 = ml[mi1];
  const float M = fmaxf(m0, m1);
  const float w0 = exp2f(m0 - M), w1 = exp2f(m1 - M);
  const float inv = 1.0f / (w0 * ml[mi0 + 1] + w1 * ml[mi1 + 1]);
  const size_t aoff = ((size_t)bh * 2048 + q) * 64 + d;
  const float4 a0 = *(const float4*)&accA[aoff];
  const float4 a1 = *(const float4*)&accB[aoff];
  float4 v = make_float4((w0 * a0.x + w1 * a1.x) * inv, (w0 * a0.y + w1 * a1.y) * inv,
                         (w0 * a0.z + w1 * a1.z) * inv, (w0 * a0.w + w1 * a1.w) * inv);
  ushort4 hv4, lv4;
  split4(v, hv4, lv4);
  const int b = bh >> 3, h = bh & 7;
  const size_t nrow = (size_t)q * B_ + b;
  const int col = h * 64 + d;
  *(ushort4*)&OutP[nrow * 1024 + col] = hv4;
  *(ushort4*)&OutP[nrow * 1024 + 512 + col] = lv4;
}

// ---------------------------------------------------------------------------
extern "C" void kernel_launch(void* const* d_in, const int* in_sizes, int n_in,
                              void* d_out, int out_size, void* d_ws, size_t ws_size,
                              hipStream_t stream)
{
  const float* reg_x = (const float*)d_in[0];
  const int*   ids   = (const int*)d_in[1];
  const float* table = (const float*)d_in[4];
  const float* wq1 = (const float*)d_in[5];  const float* bq1 = (const float*)d_in[6];
  const float* wq2 = (const float*)d_in[7];  const float* bq2 = (const float*)d_in[8];
  const float* wk  = (const float*)d_in[9];  const float* bk  = (const float*)d_in[10];
  const float* wv  = (const float*)d_in[11]; const float* bv  = (const float*)d_in[12];
  const float* wo  = (const float*)d_in[13]; const float* bo  = (const float*)d_in[14];
  const float* sgw = (const float*)d_in[15];
  const float* rgw = (const float*)d_in[16];
  const float* gb  = (const float*)d_in[17];
  float* out = (float*)d_out;
  char* W = (char*)d_ws;

  // ---- workspace layout (bytes), total 63,438,848 (< 66,060,288 proven-safe)
  const size_t WSLOT  = 1572864;                  // 512*1536*2
  const size_t oApair = 0;                        //  8 MB [reuse: stage-1 acc, stage-3 accA]
  const size_t oW     = 8388608;                  //  7 x 1.5 MB
  const size_t oKhi   = oW + 7 * WSLOT;           // [reuse: attn_p over Khi+Klo]
  const size_t oKlo   = oKhi + 4194304;
  const size_t oVtHi  = oKlo + 4194304;
  const size_t oVtLo  = oVtHi + 4194304;
  const size_t oQ1hi  = oVtLo + 4194304;          // [reuse: sout_p over Q1hi+Q1lo]
  const size_t oQ1lo  = oQ1hi + 4194304;
  const size_t oQ2hi  = oQ1lo + 4194304;          // [reuse: rout_p over Q2hi+Q2lo]
  const size_t oQ2lo  = oQ2hi + 4194304;
  const size_t oAcc1  = oQ2lo + 4194304;          // 8 MB, stage-3 accB
  const size_t oSQhi  = oAcc1 + 8388608;
  const size_t oSQlo  = oSQhi + 262144;
  const size_t oX2hi  = oSQlo + 262144;
  const size_t oX2lo  = oX2hi + 262144;
  const size_t oX2Thi = oX2lo + 262144;
  const size_t oX2Tlo = oX2Thi + 262144;
  const size_t oMl    = oX2Tlo + 262144;          // +524,288

  auto U16 = [&](size_t off) { return (unsigned short*)(W + off); };
  auto F32 = [&](size_t off) { return (float*)(W + off); };
  unsigned short* Apair  = U16(oApair);
  unsigned short* Wk3    = U16(oW + 0 * WSLOT);
  unsigned short* Wv3    = U16(oW + 1 * WSLOT);
  unsigned short* Wq13   = U16(oW + 2 * WSLOT);
  unsigned short* Wq23   = U16(oW + 3 * WSLOT);
  unsigned short* Wsg3   = U16(oW + 4 * WSLOT);
  unsigned short* Wrg3   = U16(oW + 5 * WSLOT);
  unsigned short* Wo3    = U16(oW + 6 * WSLOT);
  float*          accS   = F32(oApair);           // stage-1 partials; stage-3 chunk 0
  float*          accB3  = F32(oAcc1);            // stage-3 chunk 1
  float*          mlP    = F32(oMl);
  unsigned short* sout_p = U16(oQ1hi);            // Q1 dead after stage-2 flash
  unsigned short* rout_p = U16(oQ2hi);            // Q2 dead after stage-3 flash
  unsigned short* attn_p = U16(oKhi);             // K dead after stage-3 flash

  const dim3 blk(256);

  // ---- fused precision splits + gather (1 launch, vectorized)
  WSplit7 ws7;
  ws7.j[0] = WSplitJob{wk,  Wk3};
  ws7.j[1] = WSplitJob{wv,  Wv3};
  ws7.j[2] = WSplitJob{wq1, Wq13};
  ws7.j[3] = WSplitJob{wq2, Wq23};
  ws7.j[4] = WSplitJob{sgw, Wsg3};
  ws7.j[5] = WSplitJob{rgw, Wrg3};
  ws7.j[6] = WSplitJob{wo,  Wo3};
  fused_split_kernel<<<3968, blk, 0, stream>>>(reg_x, Apair, ws7, table, ids,
                                               U16(oSQhi), U16(oSQlo));

  // ---- 4 projections: m97-structure 128x128 gemm (512 blocks)
  GOuts4 proj;
  proj.o[0] = GOut{Wk3,  bk,  1.0f,    U16(oKhi),  U16(oKlo),  1};
  proj.o[1] = GOut{Wv3,  bv,  1.0f,    U16(oVtHi), U16(oVtLo), 2};
  proj.o[2] = GOut{Wq13, bq1, SLOG2E_, U16(oQ1hi), U16(oQ1lo), 1};
  proj.o[3] = GOut{Wq23, bq2, SLOG2E_, U16(oQ2hi), U16(oQ2lo), 1};
  gemm128_kernel<<<dim3(32, 4, 4), blk, 0, stream>>>(Apair, proj);

  // ---- stage 1: summary queries attend to reg tokens (16 KV chunks)
  FArgs a1;
  a1.Qhi = U16(oSQhi); a1.Qlo = U16(oSQlo);
  a1.Khi = U16(oKhi);  a1.Klo = U16(oKlo);
  a1.VtHi = U16(oVtHi); a1.VtLo = U16(oVtLo);
  a1.q_len = S_; a1.kv_len = R_; a1.chunk = 128; a1.zsplit = 16; a1.out_mode = 0;
  a1.accA = accS; a1.accB = accS; a1.mlP = mlP; a1.OutP = nullptr;
  flash_s1_kernel<<<dim3(16, 1, 16), blk, 0, stream>>>(a1);
  merge_x2_kernel<<<128, blk, 0, stream>>>(accS, mlP,
      U16(oX2hi), U16(oX2lo), U16(oX2Thi), U16(oX2Tlo));

  // ---- combined stage 3 (2 chunks, 512 blocks first) + stage 2 (256 blocks)
  FArgs a3;
  a3.Qhi = U16(oQ2hi); a3.Qlo = U16(oQ2lo);
  a3.Khi = U16(oKhi);  a3.Klo = U16(oKlo);
  a3.VtHi = U16(oVtHi); a3.VtLo = U16(oVtLo);
  a3.q_len = R_; a3.kv_len = R_; a3.chunk = 1024; a3.zsplit = 1; a3.out_mode = 0;
  a3.accA = accS; a3.accB = accB3; a3.mlP = mlP; a3.OutP = nullptr;
  FArgs a2;
  a2.Qhi = U16(oQ1hi); a2.Qlo = U16(oQ1lo);
  a2.Khi = U16(oX2hi); a2.Klo = U16(oX2lo);
  a2.VtHi = U16(oX2Thi); a2.VtLo = U16(oX2Tlo);
  a2.q_len = R_; a2.kv_len = S_; a2.chunk = 128; a2.zsplit = 1; a2.out_mode = 1;
  a2.accA = nullptr; a2.accB = nullptr; a2.mlP = mlP; a2.OutP = sout_p;
  flash_s23_kernel<<<768, blk, 0, stream>>>(a3, a2);

  // ---- merge stage-3 partials -> rout pair (vectorized)
  merge_rows_kernel<<<2048, blk, 0, stream>>>(accS, accB3, mlP, rout_p);

  // ---- fused gate GEMMs (K=1024 each) + sigmoid + blend -> attn pair
  gate_blend_gemm_kernel<<<dim3(32, 8), blk, 0, stream>>>(
      sout_p, rout_p, Wsg3, Wrg3, gb, attn_p);

  // ---- output projection -> d_out
  GemmOuts4 gf;
  gf.o[0].W = Wo3; gf.o[0].bias = bo; gf.o[0].scale = 1.0f; gf.o[0].Cf = out;
  gf.o[0].hi = nullptr; gf.o[0].lo = nullptr; gf.o[0].mode = 0;
  gf.o[1] = gf.o[0]; gf.o[2] = gf.o[0]; gf.o[3] = gf.o[0];
  gemm_split_kernel<<<dim3(32, 8, 1), blk, 0, stream>>>(attn_p, gf);
}